// Round 12
// baseline (167.950 us; speedup 1.0000x reference)
//
#include <hip/hip_runtime.h>
#include <stdint.h>

// MultiHeadSelfAttention: E=1024, H=16, S=4096, half=512, Dh=32, scale=sqrt(64)=8
// R21: R20 base (best, 159.8us) with ONE change: attn KVBLK 128->256.
// Halves barrier count again (the R16 lever, one more step): 8 tiles of 256
// keys per block at ns=2, 2-buffer Ks/Vt (72KB LDS, still 2 blocks/CU).
// Key-permutation generalizes verbatim (pb=4c+quad, pw=j; masks widen to &31
// on both write and read rotation). Staging: 2 K-rows + 2 V-rows per thread.
// GEMMs (BK=64 DMA), convert_w+xb, combine: verbatim R20.

#define SEQ    4096
#define DMODEL 1024
#define DHALF  512
#define NH     16
#define DH     32

typedef __attribute__((ext_vector_type(4))) float facc4;
typedef __attribute__((ext_vector_type(8))) short bfrag8;

#define MFMA_BF16(a, b, c) __builtin_amdgcn_mfma_f32_16x16x32_bf16((a), (b), (c), 0, 0, 0)

// global -> LDS direct DMA, 16B per lane; LDS dest = base + lane*16 (HW).
static __device__ __forceinline__ void gll16(const void* g, void* l) {
    typedef const __attribute__((address_space(1))) void GV;
    typedef __attribute__((address_space(3))) void LV;
    __builtin_amdgcn_global_load_lds((GV*)g, (LV*)l, 16, 0, 0);
}

static __device__ __forceinline__ uint16_t f2b(float x) {
    uint32_t u = __float_as_uint(x);
    return (uint16_t)((u + 0x7FFFu + ((u >> 16) & 1u)) >> 16);  // RNE
}
static __device__ __forceinline__ float b2f(uint16_t b) {
    return __uint_as_float(((uint32_t)b) << 16);
}

// 8x fp32 -> 8x bf16 (round-half-away; ties measure-small) via 2add+1perm pairs
static __device__ __forceinline__ bfrag8 cvt8perm(float4 a, float4 b) {
    uint32_t u0 = __float_as_uint(a.x) + 0x8000u, u1 = __float_as_uint(a.y) + 0x8000u;
    uint32_t u2 = __float_as_uint(a.z) + 0x8000u, u3 = __float_as_uint(a.w) + 0x8000u;
    uint32_t u4 = __float_as_uint(b.x) + 0x8000u, u5 = __float_as_uint(b.y) + 0x8000u;
    uint32_t u6 = __float_as_uint(b.z) + 0x8000u, u7 = __float_as_uint(b.w) + 0x8000u;
    union { uint32_t w[4]; bfrag8 r; } u;
    u.w[0] = __builtin_amdgcn_perm(u1, u0, 0x07060302u);
    u.w[1] = __builtin_amdgcn_perm(u3, u2, 0x07060302u);
    u.w[2] = __builtin_amdgcn_perm(u5, u4, 0x07060302u);
    u.w[3] = __builtin_amdgcn_perm(u7, u6, 0x07060302u);
    return u.r;
}

// Weights fp32->bf16: blocks [0,128) Wq, [128,256) Wk, [256,384) Wv, [384,640) Wo.
// Blocks [640,1664): x left-half fp32 -> xb bf16 (4096x512, row-major).
__global__ __launch_bounds__(256) void convert_w(
    const float* __restrict__ Wq, const float* __restrict__ Wk,
    const float* __restrict__ Wv, const float* __restrict__ Wo,
    const float* __restrict__ x,
    uint16_t* __restrict__ q, uint16_t* __restrict__ k,
    uint16_t* __restrict__ v, uint16_t* __restrict__ o,
    uint16_t* __restrict__ xb)
{
    int zz = blockIdx.x;
    if (zz >= 640) {
        size_t g = (size_t)(zz - 640) * 2048 + (size_t)threadIdx.x * 8;
        int row = (int)(g >> 9);
        int col = (int)(g & 511);
        const float* src = &x[(size_t)row * DMODEL + col];
        float4 a = *(const float4*)src;
        float4 b = *(const float4*)(src + 4);
        *(bfrag8*)&xb[g] = cvt8perm(a, b);
        return;
    }
    const float* src; uint16_t* dst; size_t off;
    if      (zz < 128) { src = Wq; dst = q; off = (size_t)zz * 2048; }
    else if (zz < 256) { src = Wk; dst = k; off = (size_t)(zz - 128) * 2048; }
    else if (zz < 384) { src = Wv; dst = v; off = (size_t)(zz - 256) * 2048; }
    else               { src = Wo; dst = o; off = (size_t)(zz - 384) * 2048; }
    size_t i = off + (size_t)threadIdx.x * 8;
    float4 a = *(const float4*)&src[i];
    float4 b = *(const float4*)&src[i + 4];
    *(bfrag8*)&dst[i] = cvt8perm(a, b);
}

// ---------------------------------------------------------------------------
// 128x128-tile bf16 GEMM, BK=64, double-buffered, global_load_lds staging.
// LDS tile: lane-linear [128 rows][64 u16]. Chunk swizzle: phys 16B chunk c of
// row r holds logical k-chunk c^(r&7); DMA source applies the inverse per lane;
// ds_read applies it on the read side. ONE barrier per 64-K. Swapped-operand
// MFMA: lane (lo,quad) holds C[row=..+lo][col=..+quad*4+r]. (R20-proven)
// ---------------------------------------------------------------------------
__device__ __forceinline__ void gemm128(
    const uint16_t* __restrict__ A, int lda,
    const uint16_t* __restrict__ B, int ldb,
    void* __restrict__ C, int ldc, int cF32,
    const float* __restrict__ bias, float scale,
    int Kd, int m0, int n0)
{
    __shared__ __align__(16) uint16_t As[2][128 * 64];
    __shared__ __align__(16) uint16_t Bs[2][128 * 64];

    const int tid  = threadIdx.x;
    const int lane = tid & 63;
    const int wv   = tid >> 6;
    const int lo   = lane & 15;
    const int quad = lane >> 4;
    const int rb   = (wv >> 1) * 64;
    const int cb   = (wv & 1) * 64;

    const facc4 ZACC = {0.f, 0.f, 0.f, 0.f};
    facc4 acc[4][4];
#pragma unroll
    for (int i = 0; i < 4; ++i)
#pragma unroll
        for (int j = 0; j < 4; ++j) acc[i][j] = ZACC;

    const int lrow8 = lane >> 3;                      // 0..7
    const int scol  = (((lane & 7) ^ lrow8) << 3);    // swizzled source k-col (u16)
    const uint16_t* gA[4];
    const uint16_t* gB[4];
#pragma unroll
    for (int ii = 0; ii < 4; ++ii) {
        gA[ii] = &A[(size_t)(m0 + wv * 32 + ii * 8 + lrow8) * lda + scol];
        gB[ii] = &B[(size_t)(n0 + wv * 32 + ii * 8 + lrow8) * ldb + scol];
    }
    const int dd[4] = { wv * 2048, wv * 2048 + 512, wv * 2048 + 1024, wv * 2048 + 1536 };

    const int rdo0 = lo * 64 + (((quad) ^ (lo & 7)) << 3);
    const int rdo1 = lo * 64 + (((4 + quad) ^ (lo & 7)) << 3);

#pragma unroll
    for (int ii = 0; ii < 4; ++ii) {
        gll16(gA[ii], &As[0][dd[ii]]);
        gll16(gB[ii], &Bs[0][dd[ii]]);
    }
    __syncthreads();   // drains vmcnt -> tile 0 resident

    int p = 0;
    for (int kt = 0; kt < Kd; kt += 64) {
        const bool more = (kt + 64 < Kd);
        if (more) {
#pragma unroll
            for (int ii = 0; ii < 4; ++ii) {
                gll16(gA[ii] + kt + 64, &As[1 - p][dd[ii]]);
                gll16(gB[ii] + kt + 64, &Bs[1 - p][dd[ii]]);
            }
        }

        {   // k-half 0
            bfrag8 af[4], bf[4];
#pragma unroll
            for (int i = 0; i < 4; ++i) {
                af[i] = *(const bfrag8*)&As[p][rb * 64 + i * 1024 + rdo0];
                bf[i] = *(const bfrag8*)&Bs[p][cb * 64 + i * 1024 + rdo0];
            }
#pragma unroll
            for (int i = 0; i < 4; ++i)
#pragma unroll
                for (int j = 0; j < 4; ++j)
                    acc[i][j] = MFMA_BF16(bf[j], af[i], acc[i][j]);  // swapped
        }
        {   // k-half 1
            bfrag8 af[4], bf[4];
#pragma unroll
            for (int i = 0; i < 4; ++i) {
                af[i] = *(const bfrag8*)&As[p][rb * 64 + i * 1024 + rdo1];
                bf[i] = *(const bfrag8*)&Bs[p][cb * 64 + i * 1024 + rdo1];
            }
#pragma unroll
            for (int i = 0; i < 4; ++i)
#pragma unroll
                for (int j = 0; j < 4; ++j)
                    acc[i][j] = MFMA_BF16(bf[j], af[i], acc[i][j]);  // swapped
        }

        if (more) {
            __syncthreads();  // the only barrier per 64-K iter
            p ^= 1;
        }
    }

#pragma unroll
    for (int i = 0; i < 4; ++i) {
        const size_t row = (size_t)(m0 + rb + i * 16 + lo);
#pragma unroll
        for (int j = 0; j < 4; ++j) {
            const int colb = n0 + cb + j * 16 + quad * 4;
            float4 bv = {0.f, 0.f, 0.f, 0.f};
            if (bias) bv = *(const float4*)&bias[colb];
            float v0 = acc[i][j][0] * scale + bv.x;
            float v1 = acc[i][j][1] * scale + bv.y;
            float v2 = acc[i][j][2] * scale + bv.z;
            float v3 = acc[i][j][3] * scale + bv.w;
            if (cF32) {
                float4 o = {v0, v1, v2, v3};
                *(float4*)&((float*)C)[row * ldc + colb] = o;
            } else {
                uint2 o;
                o.x = (uint32_t)f2b(v0) | ((uint32_t)f2b(v1) << 16);
                o.y = (uint32_t)f2b(v2) | ((uint32_t)f2b(v3) << 16);
                *(uint2*)&((uint16_t*)C)[row * ldc + colb] = o;
            }
        }
    }
}

#define SC_Q (0.125f * 1.4426950408889634f)  // softmax scale * log2(e), folded into Q

// QKV from pre-converted bf16 xb. Grid (4, 32, 3).
__global__ __launch_bounds__(256, 2) void qkv_kernel(
    const uint16_t* __restrict__ xb,
    const uint16_t* __restrict__ Wqb, const uint16_t* __restrict__ Wkb,
    const uint16_t* __restrict__ Wvb,
    uint16_t* __restrict__ Q, uint16_t* __restrict__ K, uint16_t* __restrict__ V)
{
    const int z = blockIdx.z;
    const uint16_t* W = (z == 0) ? Wqb : (z == 1) ? Wkb : Wvb;
    uint16_t* Out     = (z == 0) ? Q   : (z == 1) ? K   : V;
    float scale       = (z == 0) ? SC_Q : 1.0f;
    gemm128(xb, DHALF, W, DHALF, Out, DHALF, 0, nullptr, scale, DHALF,
            blockIdx.y * 128, blockIdx.x * 128);
}

// Grid (8, 32).
__global__ __launch_bounds__(256, 2) void outproj_kernel(
    const uint16_t* __restrict__ O, const uint16_t* __restrict__ Wob,
    const float* __restrict__ bo, float* __restrict__ Y)
{
    gemm128(O, DHALF, Wob, DHALF, Y, DMODEL, 1, bo, 1.0f, DHALF,
            blockIdx.y * 128, blockIdx.x * 128);
}

// ---------------------------------------------------------------------------
// Split-K flash attention, KVBLK=256 (R21), ns=2. 512 threads / 8 waves; each
// wave owns 32 q-rows (q-block 256); 256-key tile as four 64-key groups. P in
// registers: swapped QK^T mfma(K,Q) gives lane (lo,quad) P[q=lo] at keys
// 64G+16t+4quad+r; V staged key-permuted (pb=4c+quad group, pw=j within) so
// PV's B-slot order matches P's register order; rotation masks &31 on BOTH
// write and read sides. 2-buffer Ks/Vt (72KB), 1 barrier per 256-key tile.
// XCD panel swizzle: the 16 blocks sharing a (h,sp) panel share f mod 8.
// ---------------------------------------------------------------------------
__global__ __launch_bounds__(512) void attn_kernel(
    const uint16_t* __restrict__ Q, const uint16_t* __restrict__ Kb,
    const uint16_t* __restrict__ Vb, uint16_t* __restrict__ Op,
    float* __restrict__ lbuf, int kspan)
{
    __shared__ __align__(16) uint16_t Ks[2][256 * 40];  // K tile [key][d]
    __shared__ __align__(16) uint16_t Vt[2][32 * 256];  // V^T [d][perm(key)], swizzled

    const int tid  = threadIdx.x;
    const int lane = tid & 63;
    const int wv   = tid >> 6;          // 0..7
    const int lo   = lane & 15;
    const int quad = lane >> 4;

    const int f  = blockIdx.x + 16 * blockIdx.y + 256 * blockIdx.z;
    const int pp = (f & 7) | ((f >> 7) << 3);
    const int h  = pp & 15;
    const int sp = pp >> 4;
    const int q0 = ((f >> 3) & 15) * 256;

    const int srow = tid >> 2;          // 0..127; this thread stages K/V rows srow, srow+128
    const int skq  = (tid & 3) * 8;

    const facc4 ZACC = {0.f, 0.f, 0.f, 0.f};

    bfrag8 qf[2];
    qf[0] = *(const bfrag8*)&Q[(size_t)(q0 + wv * 32 + lo) * DHALF + h * DH + quad * 8];
    qf[1] = *(const bfrag8*)&Q[(size_t)(q0 + wv * 32 + 16 + lo) * DHALF + h * DH + quad * 8];

    bfrag8 ones;
#pragma unroll
    for (int j = 0; j < 8; ++j) ones[j] = (short)0x3F80;  // bf16 1.0

    // V staging scatter for rows srow and srow+128: key r -> group pb(r)=4c+q,
    // within-group pw(r)=j; per-d Rd rotation (mod-32 on groups) spreads banks.
    int vt_w0[8], vt_w1[8];
    {
        int r0 = srow, r1 = srow + 128;
        int pb0 = ((r0 >> 5) << 2) | ((r0 >> 2) & 3);
        int pw0 = (((r0 >> 4) & 1) << 2) | (r0 & 3);
        int pb1 = ((r1 >> 5) << 2) | ((r1 >> 2) & 3);
        int pw1 = (((r1 >> 4) & 1) << 2) | (r1 & 3);
#pragma unroll
        for (int j = 0; j < 8; ++j) {
            int d  = skq + j;
            int Rd = ((d & 7) + 2 * (d >> 3)) & 7;
            vt_w0[j] = d * 256 + (((pb0 + Rd) & 31) << 3) + pw0;
            vt_w1[j] = d * 256 + (((pb1 + Rd) & 31) << 3) + pw1;
        }
    }
    int vt_r[8][2];
#pragma unroll
    for (int dt = 0; dt < 2; ++dt) {
        int d  = dt * 16 + lo;
        int Rd = ((d & 7) + 2 * (d >> 3)) & 7;
#pragma unroll
        for (int c = 0; c < 8; ++c)
            vt_r[c][dt] = d * 256 + ((((c * 4 + quad) + Rd) & 31) << 3);
    }
    const int ks_r = lo * 40 + quad * 8;

    const uint16_t* kp = &Kb[(size_t)(sp * kspan + srow) * DHALF + h * DH + skq];
    const uint16_t* vp = &Vb[(size_t)(sp * kspan + srow) * DHALF + h * DH + skq];

    facc4 oacc[2][2], oaccL[2];
    oacc[0][0] = ZACC; oacc[0][1] = ZACC;
    oacc[1][0] = ZACC; oacc[1][1] = ZACC;
    oaccL[0] = ZACC; oaccL[1] = ZACC;

    float4 kreg0 = *(const float4*)kp;
    float4 kreg1 = *(const float4*)(kp + (size_t)128 * DHALF);
    float4 vreg0 = *(const float4*)vp;
    float4 vreg1 = *(const float4*)(vp + (size_t)128 * DHALF);
    kp += (size_t)256 * DHALF;
    vp += (size_t)256 * DHALF;

#define LOADKV do {                                                           \
        kreg0 = *(const float4*)kp;                                           \
        kreg1 = *(const float4*)(kp + (size_t)128 * DHALF);                   \
        vreg0 = *(const float4*)vp;                                           \
        vreg1 = *(const float4*)(vp + (size_t)128 * DHALF);                   \
        kp += (size_t)256 * DHALF; vp += (size_t)256 * DHALF;                 \
    } while (0)

#define STAGE(BUF) do {                                                       \
        *(float4*)&Ks[BUF][srow * 40 + skq] = kreg0;                          \
        *(float4*)&Ks[BUF][(srow + 128) * 40 + skq] = kreg1;                  \
        const uint16_t* vsp0 = (const uint16_t*)&vreg0;                       \
        const uint16_t* vsp1 = (const uint16_t*)&vreg1;                       \
        _Pragma("unroll")                                                     \
        for (int j = 0; j < 8; ++j) Vt[BUF][vt_w0[j]] = vsp0[j];              \
        _Pragma("unroll")                                                     \
        for (int j = 0; j < 8; ++j) Vt[BUF][vt_w1[j]] = vsp1[j];              \
    } while (0)

// One 64-key group (G in 0..3) of a 256-key tile: QK^T + exp + pack + PV.
#define GROUP(BUF, G) do {                                                    \
        uint2 w0[4], w1[4];                                                   \
        _Pragma("unroll")                                                     \
        for (int t4 = 0; t4 < 4; ++t4) {                                      \
            bfrag8 kf = *(const bfrag8*)&Ks[BUF][(4 * (G) + t4) * 640 + ks_r];\
            facc4 s0 = MFMA_BF16(kf, qf[0], ZACC);                            \
            facc4 s1 = MFMA_BF16(kf, qf[1], ZACC);                            \
            uint32_t a0 = __float_as_uint(__builtin_amdgcn_exp2f(s0[0])) + 0x8000u; \
            uint32_t a1 = __float_as_uint(__builtin_amdgcn_exp2f(s0[1])) + 0x8000u; \
            uint32_t a2 = __float_as_uint(__builtin_amdgcn_exp2f(s0[2])) + 0x8000u; \
            uint32_t a3 = __float_as_uint(__builtin_amdgcn_exp2f(s0[3])) + 0x8000u; \
            w0[t4].x = __builtin_amdgcn_perm(a1, a0, 0x07060302u);            \
            w0[t4].y = __builtin_amdgcn_perm(a3, a2, 0x07060302u);            \
            uint32_t b0 = __float_as_uint(__builtin_amdgcn_exp2f(s1[0])) + 0x8000u; \
            uint32_t b1 = __float_as_uint(__builtin_amdgcn_exp2f(s1[1])) + 0x8000u; \
            uint32_t b2 = __float_as_uint(__builtin_amdgcn_exp2f(s1[2])) + 0x8000u; \
            uint32_t b3 = __float_as_uint(__builtin_amdgcn_exp2f(s1[3])) + 0x8000u; \
            w1[t4].x = __builtin_amdgcn_perm(b1, b0, 0x07060302u);            \
            w1[t4].y = __builtin_amdgcn_perm(b3, b2, 0x07060302u);            \
        }                                                                     \
        union PU { uint2 u2[2]; bfrag8 f; } pu;                               \
        bfrag8 pf0[2], pf1[2];                                                \
        pu.u2[0] = w0[0]; pu.u2[1] = w0[1]; pf0[0] = pu.f;                    \
        pu.u2[0] = w0[2]; pu.u2[1] = w0[3]; pf0[1] = pu.f;                    \
        pu.u2[0] = w1[0]; pu.u2[1] = w1[1]; pf1[0] = pu.f;                    \
        pu.u2[0] = w1[2]; pu.u2[1] = w1[3]; pf1[1] = pu.f;                    \
        _Pragma("unroll")                                                     \
        for (int cc = 0; cc < 2; ++cc) {                                      \
            _Pragma("unroll")                                                 \
            for (int dt = 0; dt < 2; ++dt) {                                  \
                bfrag8 vf = *(const bfrag8*)&Vt[BUF][vt_r[2 * (G) + cc][dt]]; \
                oacc[0][dt] = MFMA_BF16(pf0[cc], vf, oacc[0][dt]);            \
                oacc[1][dt] = MFMA_BF16(pf1[cc], vf, oacc[1][dt]);            \
            }                                                                 \
            oaccL[0] = MFMA_BF16(pf0[cc], ones, oaccL[0]);                    \
            oaccL[1] = MFMA_BF16(pf1[cc], ones, oaccL[1]);                    \
        }                                                                     \
    } while (0)

#define TILE(BUF) do { GROUP(BUF, 0); GROUP(BUF, 1); GROUP(BUF, 2); GROUP(BUF, 3); } while (0)

    STAGE(0);
    __syncthreads();

    const int nt = kspan >> 8;  // 8 at ns=2; always even
    for (int t = 0; t < nt; t += 2) {
        LOADKV;                 // prefetch tile t+1 (always exists: nt even)
        TILE(0);
        STAGE(1);
        __syncthreads();

        const bool more = (t + 2 < nt);
        if (more) LOADKV;       // prefetch tile t+2
        TILE(1);
        if (more) {
            STAGE(0);
            __syncthreads();
        }
    }
#undef LOADKV
#undef STAGE
#undef GROUP
#undef TILE

    // l for q-row (g*16 + quad*4 + r) sits in oaccL[g][r] (same on all lo lanes)
    if (lo == 0) {
#pragma unroll
        for (int g = 0; g < 2; ++g)
#pragma unroll
            for (int r = 0; r < 4; ++r)
                lbuf[((size_t)sp * NH + h) * SEQ + q0 + wv * 32 + g * 16 + quad * 4 + r] =
                    oaccL[g][r];
    }

    uint16_t* Od = Op + (size_t)sp * SEQ * DHALF;
#pragma unroll
    for (int g = 0; g < 2; ++g) {
#pragma unroll
        for (int r = 0; r < 4; ++r) {
            int row = q0 + wv * 32 + g * 16 + quad * 4 + r;
            Od[(size_t)row * DHALF + h * DH + lo]      = f2b(oacc[g][0][r]);  // unnormalized
            Od[(size_t)row * DHALF + h * DH + 16 + lo] = f2b(oacc[g][1][r]);
        }
    }
}

// O = sum_sp(Op_sp) / sum_sp(l_sp); 1 thread = 8 cols (within one head).
__global__ __launch_bounds__(256) void combine_kernel(
    const uint16_t* __restrict__ Op, const float* __restrict__ lbuf,
    uint16_t* __restrict__ O, int ns)
{
    int t   = blockIdx.x * 256 + threadIdx.x;
    int row = t >> 6;
    int cb  = (t & 63) << 3;
    int h   = cb >> 5;
    float l = 0.f;
    float acc[8] = {0.f, 0.f, 0.f, 0.f, 0.f, 0.f, 0.f, 0.f};
    for (int sp = 0; sp < ns; ++sp) {
        l += lbuf[((size_t)sp * NH + h) * SEQ + row];
        bfrag8 a = *(const bfrag8*)&Op[(size_t)sp * SEQ * DHALF + (size_t)row * DHALF + cb];
#pragma unroll
        for (int j = 0; j < 8; ++j) acc[j] += b2f((uint16_t)a[j]);
    }
    float inv = 1.0f / l;
    bfrag8 o;
#pragma unroll
    for (int j = 0; j < 8; ++j) o[j] = (short)f2b(acc[j] * inv);
    *(bfrag8*)&O[(size_t)row * DHALF + cb] = o;
}

extern "C" void kernel_launch(void* const* d_in, const int* in_sizes, int n_in,
                              void* d_out, int out_size, void* d_ws, size_t ws_size,
                              hipStream_t stream)
{
    const float* x  = (const float*)d_in[0];
    const float* Wq = (const float*)d_in[1];
    const float* Wk = (const float*)d_in[2];
    const float* Wv = (const float*)d_in[3];
    const float* Wo = (const float*)d_in[4];
    const float* bo = (const float*)d_in[5];

    // ws (u16 elems): Wqb/Wkb/Wvb 256K ea | Wob 512K | Q,K,V,O 2M ea | Op ns*2M
    // then lbuf (ns*NH*SEQ fp32). xb (bf16 x left half) aliases the O slot:
    // written by convert_w, read by qkv, dead before combine writes O.
    const int ns = 2;

    uint16_t* Wqb = (uint16_t*)d_ws;
    uint16_t* Wkb = Wqb + (size_t)DHALF * DHALF;
    uint16_t* Wvb = Wkb + (size_t)DHALF * DHALF;
    uint16_t* Wob = Wvb + (size_t)DHALF * DHALF;
    uint16_t* Q   = Wob + (size_t)DMODEL * DHALF;
    uint16_t* K   = Q + (size_t)SEQ * DHALF;
    uint16_t* V   = K + (size_t)SEQ * DHALF;
    uint16_t* O   = V + (size_t)SEQ * DHALF;
    uint16_t* Op  = O + (size_t)SEQ * DHALF;
    float*  lbuf  = (float*)(Op + (size_t)ns * SEQ * DHALF);
    uint16_t* xb  = O;  // alias: live only convert_w -> qkv

    convert_w<<<1664, 256, 0, stream>>>(Wq, Wk, Wv, Wo, x, Wqb, Wkb, Wvb, Wob, xb);
    qkv_kernel<<<dim3(DHALF / 128, SEQ / 128, 3), 256, 0, stream>>>(
        xb, Wqb, Wkb, Wvb, Q, K, V);
    attn_kernel<<<dim3(SEQ / 256, NH, ns), 512, 0, stream>>>(Q, K, V, Op, lbuf, SEQ / ns);
    combine_kernel<<<1024, 256, 0, stream>>>(Op, lbuf, O, ns);
    outproj_kernel<<<dim3(DMODEL / 128, SEQ / 128), 256, 0, stream>>>(
        O, Wob, bo, (float*)d_out);
}

// Round 16
// 165.775 us; speedup vs baseline: 1.0131x; 1.0131x over previous
//
#include <hip/hip_runtime.h>
#include <stdint.h>

// MultiHeadSelfAttention: E=1024, H=16, S=4096, half=512, Dh=32, scale=sqrt(64)=8
// R23b (3rd submit; R14/R15 rounds were infra failures, no data; launch_bounds
// min-wave hint dropped as the only compile-directive delta vs proven R20):
// R20 base with ONE attn change: waves split the 128-key tile by half.
// wave = (qgrp 0..3, keyhalf 0..1); per-wave register structure is VERBATIM
// R20 (qf[2], oacc[2][2], oaccL[2], ~56 VGPR) but each wave reads only its
// key-half's kf/vf fragments -> per-q LDS read traffic halves (all 8 waves
// previously issued IDENTICAL ds_read streams = 8x amplification). Block
// q-tile 256->128, grid 512->1024 blocks = 4 blocks/CU = 32 waves/CU.
// Key-half partials merged once at the end through reused LDS.
// GEMMs (BK=64 DMA), convert_w+xb, combine: verbatim R20. ns=2.

#define SEQ    4096
#define DMODEL 1024
#define DHALF  512
#define NH     16
#define DH     32

typedef __attribute__((ext_vector_type(4))) float facc4;
typedef __attribute__((ext_vector_type(8))) short bfrag8;

#define MFMA_BF16(a, b, c) __builtin_amdgcn_mfma_f32_16x16x32_bf16((a), (b), (c), 0, 0, 0)

// global -> LDS direct DMA, 16B per lane; LDS dest = base + lane*16 (HW).
static __device__ __forceinline__ void gll16(const void* g, void* l) {
    typedef const __attribute__((address_space(1))) void GV;
    typedef __attribute__((address_space(3))) void LV;
    __builtin_amdgcn_global_load_lds((GV*)g, (LV*)l, 16, 0, 0);
}

static __device__ __forceinline__ uint16_t f2b(float x) {
    uint32_t u = __float_as_uint(x);
    return (uint16_t)((u + 0x7FFFu + ((u >> 16) & 1u)) >> 16);  // RNE
}
static __device__ __forceinline__ float b2f(uint16_t b) {
    return __uint_as_float(((uint32_t)b) << 16);
}

// 8x fp32 -> 8x bf16 (round-half-away; ties measure-small) via 2add+1perm pairs
static __device__ __forceinline__ bfrag8 cvt8perm(float4 a, float4 b) {
    uint32_t u0 = __float_as_uint(a.x) + 0x8000u, u1 = __float_as_uint(a.y) + 0x8000u;
    uint32_t u2 = __float_as_uint(a.z) + 0x8000u, u3 = __float_as_uint(a.w) + 0x8000u;
    uint32_t u4 = __float_as_uint(b.x) + 0x8000u, u5 = __float_as_uint(b.y) + 0x8000u;
    uint32_t u6 = __float_as_uint(b.z) + 0x8000u, u7 = __float_as_uint(b.w) + 0x8000u;
    union { uint32_t w[4]; bfrag8 r; } u;
    u.w[0] = __builtin_amdgcn_perm(u1, u0, 0x07060302u);
    u.w[1] = __builtin_amdgcn_perm(u3, u2, 0x07060302u);
    u.w[2] = __builtin_amdgcn_perm(u5, u4, 0x07060302u);
    u.w[3] = __builtin_amdgcn_perm(u7, u6, 0x07060302u);
    return u.r;
}

// Weights fp32->bf16: blocks [0,128) Wq, [128,256) Wk, [256,384) Wv, [384,640) Wo.
// Blocks [640,1664): x left-half fp32 -> xb bf16 (4096x512, row-major).
__global__ __launch_bounds__(256) void convert_w(
    const float* __restrict__ Wq, const float* __restrict__ Wk,
    const float* __restrict__ Wv, const float* __restrict__ Wo,
    const float* __restrict__ x,
    uint16_t* __restrict__ q, uint16_t* __restrict__ k,
    uint16_t* __restrict__ v, uint16_t* __restrict__ o,
    uint16_t* __restrict__ xb)
{
    int zz = blockIdx.x;
    if (zz >= 640) {
        size_t g = (size_t)(zz - 640) * 2048 + (size_t)threadIdx.x * 8;
        int row = (int)(g >> 9);
        int col = (int)(g & 511);
        const float* src = &x[(size_t)row * DMODEL + col];
        float4 a = *(const float4*)src;
        float4 b = *(const float4*)(src + 4);
        *(bfrag8*)&xb[g] = cvt8perm(a, b);
        return;
    }
    const float* src; uint16_t* dst; size_t off;
    if      (zz < 128) { src = Wq; dst = q; off = (size_t)zz * 2048; }
    else if (zz < 256) { src = Wk; dst = k; off = (size_t)(zz - 128) * 2048; }
    else if (zz < 384) { src = Wv; dst = v; off = (size_t)(zz - 256) * 2048; }
    else               { src = Wo; dst = o; off = (size_t)(zz - 384) * 2048; }
    size_t i = off + (size_t)threadIdx.x * 8;
    float4 a = *(const float4*)&src[i];
    float4 b = *(const float4*)&src[i + 4];
    *(bfrag8*)&dst[i] = cvt8perm(a, b);
}

// ---------------------------------------------------------------------------
// 128x128-tile bf16 GEMM, BK=64, double-buffered, global_load_lds staging.
// LDS tile: lane-linear [128 rows][64 u16]. Chunk swizzle: phys 16B chunk c of
// row r holds logical k-chunk c^(r&7); DMA source applies the inverse per lane;
// ds_read applies it on the read side. ONE barrier per 64-K. Swapped-operand
// MFMA: lane (lo,quad) holds C[row=..+lo][col=..+quad*4+r]. (R20-proven)
// ---------------------------------------------------------------------------
__device__ __forceinline__ void gemm128(
    const uint16_t* __restrict__ A, int lda,
    const uint16_t* __restrict__ B, int ldb,
    void* __restrict__ C, int ldc, int cF32,
    const float* __restrict__ bias, float scale,
    int Kd, int m0, int n0)
{
    __shared__ __align__(16) uint16_t As[2][128 * 64];
    __shared__ __align__(16) uint16_t Bs[2][128 * 64];

    const int tid  = threadIdx.x;
    const int lane = tid & 63;
    const int wv   = tid >> 6;
    const int lo   = lane & 15;
    const int quad = lane >> 4;
    const int rb   = (wv >> 1) * 64;
    const int cb   = (wv & 1) * 64;

    const facc4 ZACC = {0.f, 0.f, 0.f, 0.f};
    facc4 acc[4][4];
#pragma unroll
    for (int i = 0; i < 4; ++i)
#pragma unroll
        for (int j = 0; j < 4; ++j) acc[i][j] = ZACC;

    const int lrow8 = lane >> 3;                      // 0..7
    const int scol  = (((lane & 7) ^ lrow8) << 3);    // swizzled source k-col (u16)
    const uint16_t* gA[4];
    const uint16_t* gB[4];
#pragma unroll
    for (int ii = 0; ii < 4; ++ii) {
        gA[ii] = &A[(size_t)(m0 + wv * 32 + ii * 8 + lrow8) * lda + scol];
        gB[ii] = &B[(size_t)(n0 + wv * 32 + ii * 8 + lrow8) * ldb + scol];
    }
    const int dd[4] = { wv * 2048, wv * 2048 + 512, wv * 2048 + 1024, wv * 2048 + 1536 };

    const int rdo0 = lo * 64 + (((quad) ^ (lo & 7)) << 3);
    const int rdo1 = lo * 64 + (((4 + quad) ^ (lo & 7)) << 3);

#pragma unroll
    for (int ii = 0; ii < 4; ++ii) {
        gll16(gA[ii], &As[0][dd[ii]]);
        gll16(gB[ii], &Bs[0][dd[ii]]);
    }
    __syncthreads();   // drains vmcnt -> tile 0 resident

    int p = 0;
    for (int kt = 0; kt < Kd; kt += 64) {
        const bool more = (kt + 64 < Kd);
        if (more) {
#pragma unroll
            for (int ii = 0; ii < 4; ++ii) {
                gll16(gA[ii] + kt + 64, &As[1 - p][dd[ii]]);
                gll16(gB[ii] + kt + 64, &Bs[1 - p][dd[ii]]);
            }
        }

        {   // k-half 0
            bfrag8 af[4], bf[4];
#pragma unroll
            for (int i = 0; i < 4; ++i) {
                af[i] = *(const bfrag8*)&As[p][rb * 64 + i * 1024 + rdo0];
                bf[i] = *(const bfrag8*)&Bs[p][cb * 64 + i * 1024 + rdo0];
            }
#pragma unroll
            for (int i = 0; i < 4; ++i)
#pragma unroll
                for (int j = 0; j < 4; ++j)
                    acc[i][j] = MFMA_BF16(bf[j], af[i], acc[i][j]);  // swapped
        }
        {   // k-half 1
            bfrag8 af[4], bf[4];
#pragma unroll
            for (int i = 0; i < 4; ++i) {
                af[i] = *(const bfrag8*)&As[p][rb * 64 + i * 1024 + rdo1];
                bf[i] = *(const bfrag8*)&Bs[p][cb * 64 + i * 1024 + rdo1];
            }
#pragma unroll
            for (int i = 0; i < 4; ++i)
#pragma unroll
                for (int j = 0; j < 4; ++j)
                    acc[i][j] = MFMA_BF16(bf[j], af[i], acc[i][j]);  // swapped
        }

        if (more) {
            __syncthreads();  // the only barrier per 64-K iter
            p ^= 1;
        }
    }

#pragma unroll
    for (int i = 0; i < 4; ++i) {
        const size_t row = (size_t)(m0 + rb + i * 16 + lo);
#pragma unroll
        for (int j = 0; j < 4; ++j) {
            const int colb = n0 + cb + j * 16 + quad * 4;
            float4 bv = {0.f, 0.f, 0.f, 0.f};
            if (bias) bv = *(const float4*)&bias[colb];
            float v0 = acc[i][j][0] * scale + bv.x;
            float v1 = acc[i][j][1] * scale + bv.y;
            float v2 = acc[i][j][2] * scale + bv.z;
            float v3 = acc[i][j][3] * scale + bv.w;
            if (cF32) {
                float4 o = {v0, v1, v2, v3};
                *(float4*)&((float*)C)[row * ldc + colb] = o;
            } else {
                uint2 o;
                o.x = (uint32_t)f2b(v0) | ((uint32_t)f2b(v1) << 16);
                o.y = (uint32_t)f2b(v2) | ((uint32_t)f2b(v3) << 16);
                *(uint2*)&((uint16_t*)C)[row * ldc + colb] = o;
            }
        }
    }
}

#define SC_Q (0.125f * 1.4426950408889634f)  // softmax scale * log2(e), folded into Q

// QKV from pre-converted bf16 xb. Grid (4, 32, 3).
__global__ __launch_bounds__(256, 2) void qkv_kernel(
    const uint16_t* __restrict__ xb,
    const uint16_t* __restrict__ Wqb, const uint16_t* __restrict__ Wkb,
    const uint16_t* __restrict__ Wvb,
    uint16_t* __restrict__ Q, uint16_t* __restrict__ K, uint16_t* __restrict__ V)
{
    const int z = blockIdx.z;
    const uint16_t* W = (z == 0) ? Wqb : (z == 1) ? Wkb : Wvb;
    uint16_t* Out     = (z == 0) ? Q   : (z == 1) ? K   : V;
    float scale       = (z == 0) ? SC_Q : 1.0f;
    gemm128(xb, DHALF, W, DHALF, Out, DHALF, 0, nullptr, scale, DHALF,
            blockIdx.y * 128, blockIdx.x * 128);
}

// Grid (8, 32).
__global__ __launch_bounds__(256, 2) void outproj_kernel(
    const uint16_t* __restrict__ O, const uint16_t* __restrict__ Wob,
    const float* __restrict__ bo, float* __restrict__ Y)
{
    gemm128(O, DHALF, Wob, DHALF, Y, DMODEL, 1, bo, 1.0f, DHALF,
            blockIdx.y * 128, blockIdx.x * 128);
}

// ---------------------------------------------------------------------------
// Split-K flash attention, key-half wave split (R23), ns=2.
// 512 threads / 8 waves; wave = (qgrp=wv&3, kh=wv>>2). Each wave owns 32
// q-rows (qgrp) and processes ONLY key-half kh of each 128-key tile (R20's
// per-wave register structure verbatim; ks_r/vt_r carry the kh offset).
// Block q-tile = 128; grid (32,16,2) = 1024 blocks = 4/CU = 32 waves/CU.
// Key-half partials (oacc, oaccL) merged once at the end via reused LDS.
// P in registers via key-permuted V staging; XCD panel swizzle.
// ---------------------------------------------------------------------------
__global__ __launch_bounds__(512) void attn_kernel(
    const uint16_t* __restrict__ Q, const uint16_t* __restrict__ Kb,
    const uint16_t* __restrict__ Vb, uint16_t* __restrict__ Op,
    float* __restrict__ lbuf, int kspan)
{
    __shared__ __align__(16) uint16_t Ks[2][128 * 40];  // K tile [key][d]
    __shared__ __align__(16) uint16_t Vt[2][32 * 128];  // V^T [d][perm(key)], swizzled

    const int tid  = threadIdx.x;
    const int lane = tid & 63;
    const int wv   = tid >> 6;          // 0..7
    const int lo   = lane & 15;
    const int quad = lane >> 4;
    const int qg   = wv & 3;            // q-group (32 rows each)
    const int kh   = wv >> 2;           // key-half of each tile

    // XCD panel swizzle: grid (32,16,2); f = bx + 32*by + 512*bz.
    // pp = (f&7)|((f>>8)<<3); all 32 blocks of panel pp share f mod 8.
    const int f  = blockIdx.x + 32 * blockIdx.y + 512 * blockIdx.z;
    const int pp = (f & 7) | ((f >> 8) << 3);
    const int h  = pp & 15;
    const int sp = pp >> 4;
    const int q0 = ((f >> 3) & 31) * 128;

    const int srow = tid >> 2;          // 0..127: staged K/V key row
    const int skq  = (tid & 3) * 8;

    const facc4 ZACC = {0.f, 0.f, 0.f, 0.f};

    bfrag8 qf[2];
    qf[0] = *(const bfrag8*)&Q[(size_t)(q0 + qg * 32 + lo) * DHALF + h * DH + quad * 8];
    qf[1] = *(const bfrag8*)&Q[(size_t)(q0 + qg * 32 + 16 + lo) * DHALF + h * DH + quad * 8];

    bfrag8 ones;
#pragma unroll
    for (int j = 0; j < 8; ++j) ones[j] = (short)0x3F80;  // bf16 1.0

    int vt_w[8];
    {
        int pb = ((srow >> 5) << 2) | ((srow >> 2) & 3);   // p >> 3, 0..15
        int pw = (((srow >> 4) & 1) << 2) | (srow & 3);    // p & 7
#pragma unroll
        for (int j = 0; j < 8; ++j) {
            int d  = skq + j;
            int Rd = ((d & 7) + 2 * (d >> 3)) & 7;
            vt_w[j] = d * 128 + (((pb + Rd) & 15) << 3) + pw;
        }
    }
    // reads: this wave's key-half only (c = 2*kh + cc)
    int vt_r[2][2];
#pragma unroll
    for (int dt = 0; dt < 2; ++dt) {
        int d  = dt * 16 + lo;
        int Rd = ((d & 7) + 2 * (d >> 3)) & 7;
#pragma unroll
        for (int cc = 0; cc < 2; ++cc)
            vt_r[cc][dt] = d * 128 + (((((2 * kh + cc) * 4 + quad) + Rd) & 15) << 3);
    }
    const int ks_r = kh * 2560 + lo * 40 + quad * 8;   // kh*4 t4-rows offset

    const uint16_t* kp = &Kb[(size_t)(sp * kspan + srow) * DHALF + h * DH + skq];
    const uint16_t* vp = &Vb[(size_t)(sp * kspan + srow) * DHALF + h * DH + skq];

    facc4 oacc[2][2], oaccL[2];
    oacc[0][0] = ZACC; oacc[0][1] = ZACC;
    oacc[1][0] = ZACC; oacc[1][1] = ZACC;
    oaccL[0] = ZACC; oaccL[1] = ZACC;

    float4 kreg = *(const float4*)kp;
    float4 vreg = *(const float4*)vp;
    kp += 128 * DHALF;
    vp += 128 * DHALF;

#define STAGE(BUF) do {                                                       \
        *(float4*)&Ks[BUF][srow * 40 + skq] = kreg;                           \
        const uint16_t* vsp = (const uint16_t*)&vreg;                         \
        _Pragma("unroll")                                                     \
        for (int j = 0; j < 8; ++j) Vt[BUF][vt_w[j]] = vsp[j];                \
    } while (0)

// This wave's key-half of a 128-key tile: QK^T + exp + pack + PV.
#define HALFK(BUF) do {                                                       \
        uint2 w0[4], w1[4];                                                   \
        _Pragma("unroll")                                                     \
        for (int t4 = 0; t4 < 4; ++t4) {                                      \
            bfrag8 kf = *(const bfrag8*)&Ks[BUF][t4 * 640 + ks_r];            \
            facc4 s0 = MFMA_BF16(kf, qf[0], ZACC);                            \
            facc4 s1 = MFMA_BF16(kf, qf[1], ZACC);                            \
            uint32_t a0 = __float_as_uint(__builtin_amdgcn_exp2f(s0[0])) + 0x8000u; \
            uint32_t a1 = __float_as_uint(__builtin_amdgcn_exp2f(s0[1])) + 0x8000u; \
            uint32_t a2 = __float_as_uint(__builtin_amdgcn_exp2f(s0[2])) + 0x8000u; \
            uint32_t a3 = __float_as_uint(__builtin_amdgcn_exp2f(s0[3])) + 0x8000u; \
            w0[t4].x = __builtin_amdgcn_perm(a1, a0, 0x07060302u);            \
            w0[t4].y = __builtin_amdgcn_perm(a3, a2, 0x07060302u);            \
            uint32_t b0 = __float_as_uint(__builtin_amdgcn_exp2f(s1[0])) + 0x8000u; \
            uint32_t b1 = __float_as_uint(__builtin_amdgcn_exp2f(s1[1])) + 0x8000u; \
            uint32_t b2 = __float_as_uint(__builtin_amdgcn_exp2f(s1[2])) + 0x8000u; \
            uint32_t b3 = __float_as_uint(__builtin_amdgcn_exp2f(s1[3])) + 0x8000u; \
            w1[t4].x = __builtin_amdgcn_perm(b1, b0, 0x07060302u);            \
            w1[t4].y = __builtin_amdgcn_perm(b3, b2, 0x07060302u);            \
        }                                                                     \
        union PU { uint2 u2[2]; bfrag8 f; } pu;                               \
        bfrag8 pf0[2], pf1[2];                                                \
        pu.u2[0] = w0[0]; pu.u2[1] = w0[1]; pf0[0] = pu.f;                    \
        pu.u2[0] = w0[2]; pu.u2[1] = w0[3]; pf0[1] = pu.f;                    \
        pu.u2[0] = w1[0]; pu.u2[1] = w1[1]; pf1[0] = pu.f;                    \
        pu.u2[0] = w1[2]; pu.u2[1] = w1[3]; pf1[1] = pu.f;                    \
        _Pragma("unroll")                                                     \
        for (int cc = 0; cc < 2; ++cc) {                                      \
            _Pragma("unroll")                                                 \
            for (int dt = 0; dt < 2; ++dt) {                                  \
                bfrag8 vf = *(const bfrag8*)&Vt[BUF][vt_r[cc][dt]];           \
                oacc[0][dt] = MFMA_BF16(pf0[cc], vf, oacc[0][dt]);            \
                oacc[1][dt] = MFMA_BF16(pf1[cc], vf, oacc[1][dt]);            \
            }                                                                 \
            oaccL[0] = MFMA_BF16(pf0[cc], ones, oaccL[0]);                    \
            oaccL[1] = MFMA_BF16(pf1[cc], ones, oaccL[1]);                    \
        }                                                                     \
    } while (0)

    STAGE(0);
    __syncthreads();

    const int nt = kspan >> 7;  // 16 at ns=2; always even
    for (int t = 0; t < nt; t += 2) {
        kreg = *(const float4*)kp;
        vreg = *(const float4*)vp;
        kp += 128 * DHALF; vp += 128 * DHALF;
        HALFK(0);
        STAGE(1);
        __syncthreads();

        const bool more = (t + 2 < nt);
        if (more) {
            kreg = *(const float4*)kp;
            vreg = *(const float4*)vp;
            kp += 128 * DHALF; vp += 128 * DHALF;
        }
        HALFK(1);
        if (more) {
            STAGE(0);
            __syncthreads();
        }
    }
#undef STAGE
#undef HALFK

    // ---- merge key-half partials (kh=1 -> kh=0) through reused LDS ----
    __syncthreads();  // all tile reads done; safe to overwrite Ks/Vt
    {
        float* ob = (float*)&Ks[0][0];   // 20480 B (both buffers) >= 4*64*20*4
        float* lb = (float*)&Vt[0][0];   // 16384 B >= 4*64*12*4 = 12288
        float* d  = ob + (size_t)(qg * 64 + lane) * 20;
        float* dl = lb + (size_t)(qg * 64 + lane) * 12;
        if (kh == 1) {
            *(facc4*)(d + 0)  = oacc[0][0];
            *(facc4*)(d + 4)  = oacc[0][1];
            *(facc4*)(d + 8)  = oacc[1][0];
            *(facc4*)(d + 12) = oacc[1][1];
            *(facc4*)(dl + 0) = oaccL[0];
            *(facc4*)(dl + 4) = oaccL[1];
        }
        __syncthreads();
        if (kh == 0) {
            oacc[0][0] += *(const facc4*)(d + 0);
            oacc[0][1] += *(const facc4*)(d + 4);
            oacc[1][0] += *(const facc4*)(d + 8);
            oacc[1][1] += *(const facc4*)(d + 12);
            oaccL[0]   += *(const facc4*)(dl + 0);
            oaccL[1]   += *(const facc4*)(dl + 4);
        }
    }
    if (kh != 0) return;

    // l for q-row (g*16 + quad*4 + r) sits in oaccL[g][r] (same on all lo lanes)
    if (lo == 0) {
#pragma unroll
        for (int g = 0; g < 2; ++g)
#pragma unroll
            for (int r = 0; r < 4; ++r)
                lbuf[((size_t)sp * NH + h) * SEQ + q0 + qg * 32 + g * 16 + quad * 4 + r] =
                    oaccL[g][r];
    }

    uint16_t* Od = Op + (size_t)sp * SEQ * DHALF;
#pragma unroll
    for (int g = 0; g < 2; ++g) {
#pragma unroll
        for (int r = 0; r < 4; ++r) {
            int row = q0 + qg * 32 + g * 16 + quad * 4 + r;
            Od[(size_t)row * DHALF + h * DH + lo]      = f2b(oacc[g][0][r]);  // unnormalized
            Od[(size_t)row * DHALF + h * DH + 16 + lo] = f2b(oacc[g][1][r]);
        }
    }
}

// O = sum_sp(Op_sp) / sum_sp(l_sp); 1 thread = 8 cols (within one head).
__global__ __launch_bounds__(256) void combine_kernel(
    const uint16_t* __restrict__ Op, const float* __restrict__ lbuf,
    uint16_t* __restrict__ O, int ns)
{
    int t   = blockIdx.x * 256 + threadIdx.x;
    int row = t >> 6;
    int cb  = (t & 63) << 3;
    int h   = cb >> 5;
    float l = 0.f;
    float acc[8] = {0.f, 0.f, 0.f, 0.f, 0.f, 0.f, 0.f, 0.f};
    for (int sp = 0; sp < ns; ++sp) {
        l += lbuf[((size_t)sp * NH + h) * SEQ + row];
        bfrag8 a = *(const bfrag8*)&Op[(size_t)sp * SEQ * DHALF + (size_t)row * DHALF + cb];
#pragma unroll
        for (int j = 0; j < 8; ++j) acc[j] += b2f((uint16_t)a[j]);
    }
    float inv = 1.0f / l;
    bfrag8 o;
#pragma unroll
    for (int j = 0; j < 8; ++j) o[j] = (short)f2b(acc[j] * inv);
    *(bfrag8*)&O[(size_t)row * DHALF + cb] = o;
}

extern "C" void kernel_launch(void* const* d_in, const int* in_sizes, int n_in,
                              void* d_out, int out_size, void* d_ws, size_t ws_size,
                              hipStream_t stream)
{
    const float* x  = (const float*)d_in[0];
    const float* Wq = (const float*)d_in[1];
    const float* Wk = (const float*)d_in[2];
    const float* Wv = (const float*)d_in[3];
    const float* Wo = (const float*)d_in[4];
    const float* bo = (const float*)d_in[5];

    // ws (u16 elems): Wqb/Wkb/Wvb 256K ea | Wob 512K | Q,K,V,O 2M ea | Op 2x2M
    // then lbuf (2*NH*SEQ fp32). xb (bf16 x left half) aliases the O slot:
    // written by convert_w, read by qkv, dead before combine writes O.
    const int ns = 2;

    uint16_t* Wqb = (uint16_t*)d_ws;
    uint16_t* Wkb = Wqb + (size_t)DHALF * DHALF;
    uint16_t* Wvb = Wkb + (size_t)DHALF * DHALF;
    uint16_t* Wob = Wvb + (size_t)DHALF * DHALF;
    uint16_t* Q   = Wob + (size_t)DMODEL * DHALF;
    uint16_t* K   = Q + (size_t)SEQ * DHALF;
    uint16_t* V   = K + (size_t)SEQ * DHALF;
    uint16_t* O   = V + (size_t)SEQ * DHALF;
    uint16_t* Op  = O + (size_t)SEQ * DHALF;
    float*  lbuf  = (float*)(Op + (size_t)ns * SEQ * DHALF);
    uint16_t* xb  = O;  // alias: live only convert_w -> qkv

    convert_w<<<1664, 256, 0, stream>>>(Wq, Wk, Wv, Wo, x, Wqb, Wkb, Wvb, Wob, xb);
    qkv_kernel<<<dim3(DHALF / 128, SEQ / 128, 3), 256, 0, stream>>>(
        xb, Wqb, Wkb, Wvb, Q, K, V);
    attn_kernel<<<dim3(SEQ / 128, NH, ns), 512, 0, stream>>>(Q, K, V, Op, lbuf, SEQ / ns);
    combine_kernel<<<1024, 256, 0, stream>>>(Op, lbuf, O, ns);
    outproj_kernel<<<dim3(DMODEL / 128, SEQ / 128), 256, 0, stream>>>(
        O, Wob, bo, (float*)d_out);
}

// Round 17
// 160.229 us; speedup vs baseline: 1.0482x; 1.0346x over previous
//
#include <hip/hip_runtime.h>
#include <stdint.h>

// MultiHeadSelfAttention: E=1024, H=16, S=4096, half=512, Dh=32, scale=sqrt(64)=8
// R24 = R20 verbatim (best measured: 159.8us total, attn 56.6us). Locked in
// after the full exploration: every attn structural perturbation since R16
// regressed (R13 pipeline +2.4, R21 KVBLK256 +6.2, R23 key-split +7.6), and
// the non-attn side is invariant (~103us) across seven restructures.
// Structure: weights+x -> bf16 once; 128x128 BK=64 GEMMs with global_load_lds
// DMA staging and both-sides XOR chunk swizzle; split-K (ns=2) flash attention
// with 8 waves x 32 q-rows, KVBLK=128, P entirely in registers via swapped
// QK^T + key-permuted V staging, ones-column l-accumulation; XCD panel swizzle.

#define SEQ    4096
#define DMODEL 1024
#define DHALF  512
#define NH     16
#define DH     32

typedef __attribute__((ext_vector_type(4))) float facc4;
typedef __attribute__((ext_vector_type(8))) short bfrag8;

#define MFMA_BF16(a, b, c) __builtin_amdgcn_mfma_f32_16x16x32_bf16((a), (b), (c), 0, 0, 0)

// global -> LDS direct DMA, 16B per lane; LDS dest = base + lane*16 (HW).
static __device__ __forceinline__ void gll16(const void* g, void* l) {
    typedef const __attribute__((address_space(1))) void GV;
    typedef __attribute__((address_space(3))) void LV;
    __builtin_amdgcn_global_load_lds((GV*)g, (LV*)l, 16, 0, 0);
}

static __device__ __forceinline__ uint16_t f2b(float x) {
    uint32_t u = __float_as_uint(x);
    return (uint16_t)((u + 0x7FFFu + ((u >> 16) & 1u)) >> 16);  // RNE
}
static __device__ __forceinline__ float b2f(uint16_t b) {
    return __uint_as_float(((uint32_t)b) << 16);
}

// 8x fp32 -> 8x bf16 (round-half-away; ties measure-small) via 2add+1perm pairs
static __device__ __forceinline__ bfrag8 cvt8perm(float4 a, float4 b) {
    uint32_t u0 = __float_as_uint(a.x) + 0x8000u, u1 = __float_as_uint(a.y) + 0x8000u;
    uint32_t u2 = __float_as_uint(a.z) + 0x8000u, u3 = __float_as_uint(a.w) + 0x8000u;
    uint32_t u4 = __float_as_uint(b.x) + 0x8000u, u5 = __float_as_uint(b.y) + 0x8000u;
    uint32_t u6 = __float_as_uint(b.z) + 0x8000u, u7 = __float_as_uint(b.w) + 0x8000u;
    union { uint32_t w[4]; bfrag8 r; } u;
    u.w[0] = __builtin_amdgcn_perm(u1, u0, 0x07060302u);
    u.w[1] = __builtin_amdgcn_perm(u3, u2, 0x07060302u);
    u.w[2] = __builtin_amdgcn_perm(u5, u4, 0x07060302u);
    u.w[3] = __builtin_amdgcn_perm(u7, u6, 0x07060302u);
    return u.r;
}

// Weights fp32->bf16: blocks [0,128) Wq, [128,256) Wk, [256,384) Wv, [384,640) Wo.
// Blocks [640,1664): x left-half fp32 -> xb bf16 (4096x512, row-major).
__global__ __launch_bounds__(256) void convert_w(
    const float* __restrict__ Wq, const float* __restrict__ Wk,
    const float* __restrict__ Wv, const float* __restrict__ Wo,
    const float* __restrict__ x,
    uint16_t* __restrict__ q, uint16_t* __restrict__ k,
    uint16_t* __restrict__ v, uint16_t* __restrict__ o,
    uint16_t* __restrict__ xb)
{
    int zz = blockIdx.x;
    if (zz >= 640) {
        size_t g = (size_t)(zz - 640) * 2048 + (size_t)threadIdx.x * 8;
        int row = (int)(g >> 9);
        int col = (int)(g & 511);
        const float* src = &x[(size_t)row * DMODEL + col];
        float4 a = *(const float4*)src;
        float4 b = *(const float4*)(src + 4);
        *(bfrag8*)&xb[g] = cvt8perm(a, b);
        return;
    }
    const float* src; uint16_t* dst; size_t off;
    if      (zz < 128) { src = Wq; dst = q; off = (size_t)zz * 2048; }
    else if (zz < 256) { src = Wk; dst = k; off = (size_t)(zz - 128) * 2048; }
    else if (zz < 384) { src = Wv; dst = v; off = (size_t)(zz - 256) * 2048; }
    else               { src = Wo; dst = o; off = (size_t)(zz - 384) * 2048; }
    size_t i = off + (size_t)threadIdx.x * 8;
    float4 a = *(const float4*)&src[i];
    float4 b = *(const float4*)&src[i + 4];
    *(bfrag8*)&dst[i] = cvt8perm(a, b);
}

// ---------------------------------------------------------------------------
// 128x128-tile bf16 GEMM, BK=64, double-buffered, global_load_lds staging.
// LDS tile: lane-linear [128 rows][64 u16]. Chunk swizzle: phys 16B chunk c of
// row r holds logical k-chunk c^(r&7); DMA source applies the inverse per lane;
// ds_read applies it on the read side. ONE barrier per 64-K. Swapped-operand
// MFMA: lane (lo,quad) holds C[row=..+lo][col=..+quad*4+r]. (R20-proven)
// ---------------------------------------------------------------------------
__device__ __forceinline__ void gemm128(
    const uint16_t* __restrict__ A, int lda,
    const uint16_t* __restrict__ B, int ldb,
    void* __restrict__ C, int ldc, int cF32,
    const float* __restrict__ bias, float scale,
    int Kd, int m0, int n0)
{
    __shared__ __align__(16) uint16_t As[2][128 * 64];
    __shared__ __align__(16) uint16_t Bs[2][128 * 64];

    const int tid  = threadIdx.x;
    const int lane = tid & 63;
    const int wv   = tid >> 6;
    const int lo   = lane & 15;
    const int quad = lane >> 4;
    const int rb   = (wv >> 1) * 64;
    const int cb   = (wv & 1) * 64;

    const facc4 ZACC = {0.f, 0.f, 0.f, 0.f};
    facc4 acc[4][4];
#pragma unroll
    for (int i = 0; i < 4; ++i)
#pragma unroll
        for (int j = 0; j < 4; ++j) acc[i][j] = ZACC;

    const int lrow8 = lane >> 3;                      // 0..7
    const int scol  = (((lane & 7) ^ lrow8) << 3);    // swizzled source k-col (u16)
    const uint16_t* gA[4];
    const uint16_t* gB[4];
#pragma unroll
    for (int ii = 0; ii < 4; ++ii) {
        gA[ii] = &A[(size_t)(m0 + wv * 32 + ii * 8 + lrow8) * lda + scol];
        gB[ii] = &B[(size_t)(n0 + wv * 32 + ii * 8 + lrow8) * ldb + scol];
    }
    const int dd[4] = { wv * 2048, wv * 2048 + 512, wv * 2048 + 1024, wv * 2048 + 1536 };

    const int rdo0 = lo * 64 + (((quad) ^ (lo & 7)) << 3);
    const int rdo1 = lo * 64 + (((4 + quad) ^ (lo & 7)) << 3);

#pragma unroll
    for (int ii = 0; ii < 4; ++ii) {
        gll16(gA[ii], &As[0][dd[ii]]);
        gll16(gB[ii], &Bs[0][dd[ii]]);
    }
    __syncthreads();   // drains vmcnt -> tile 0 resident

    int p = 0;
    for (int kt = 0; kt < Kd; kt += 64) {
        const bool more = (kt + 64 < Kd);
        if (more) {
#pragma unroll
            for (int ii = 0; ii < 4; ++ii) {
                gll16(gA[ii] + kt + 64, &As[1 - p][dd[ii]]);
                gll16(gB[ii] + kt + 64, &Bs[1 - p][dd[ii]]);
            }
        }

        {   // k-half 0
            bfrag8 af[4], bf[4];
#pragma unroll
            for (int i = 0; i < 4; ++i) {
                af[i] = *(const bfrag8*)&As[p][rb * 64 + i * 1024 + rdo0];
                bf[i] = *(const bfrag8*)&Bs[p][cb * 64 + i * 1024 + rdo0];
            }
#pragma unroll
            for (int i = 0; i < 4; ++i)
#pragma unroll
                for (int j = 0; j < 4; ++j)
                    acc[i][j] = MFMA_BF16(bf[j], af[i], acc[i][j]);  // swapped
        }
        {   // k-half 1
            bfrag8 af[4], bf[4];
#pragma unroll
            for (int i = 0; i < 4; ++i) {
                af[i] = *(const bfrag8*)&As[p][rb * 64 + i * 1024 + rdo1];
                bf[i] = *(const bfrag8*)&Bs[p][cb * 64 + i * 1024 + rdo1];
            }
#pragma unroll
            for (int i = 0; i < 4; ++i)
#pragma unroll
                for (int j = 0; j < 4; ++j)
                    acc[i][j] = MFMA_BF16(bf[j], af[i], acc[i][j]);  // swapped
        }

        if (more) {
            __syncthreads();  // the only barrier per 64-K iter
            p ^= 1;
        }
    }

#pragma unroll
    for (int i = 0; i < 4; ++i) {
        const size_t row = (size_t)(m0 + rb + i * 16 + lo);
#pragma unroll
        for (int j = 0; j < 4; ++j) {
            const int colb = n0 + cb + j * 16 + quad * 4;
            float4 bv = {0.f, 0.f, 0.f, 0.f};
            if (bias) bv = *(const float4*)&bias[colb];
            float v0 = acc[i][j][0] * scale + bv.x;
            float v1 = acc[i][j][1] * scale + bv.y;
            float v2 = acc[i][j][2] * scale + bv.z;
            float v3 = acc[i][j][3] * scale + bv.w;
            if (cF32) {
                float4 o = {v0, v1, v2, v3};
                *(float4*)&((float*)C)[row * ldc + colb] = o;
            } else {
                uint2 o;
                o.x = (uint32_t)f2b(v0) | ((uint32_t)f2b(v1) << 16);
                o.y = (uint32_t)f2b(v2) | ((uint32_t)f2b(v3) << 16);
                *(uint2*)&((uint16_t*)C)[row * ldc + colb] = o;
            }
        }
    }
}

#define SC_Q (0.125f * 1.4426950408889634f)  // softmax scale * log2(e), folded into Q

// QKV from pre-converted bf16 xb. Grid (4, 32, 3).
__global__ __launch_bounds__(256, 2) void qkv_kernel(
    const uint16_t* __restrict__ xb,
    const uint16_t* __restrict__ Wqb, const uint16_t* __restrict__ Wkb,
    const uint16_t* __restrict__ Wvb,
    uint16_t* __restrict__ Q, uint16_t* __restrict__ K, uint16_t* __restrict__ V)
{
    const int z = blockIdx.z;
    const uint16_t* W = (z == 0) ? Wqb : (z == 1) ? Wkb : Wvb;
    uint16_t* Out     = (z == 0) ? Q   : (z == 1) ? K   : V;
    float scale       = (z == 0) ? SC_Q : 1.0f;
    gemm128(xb, DHALF, W, DHALF, Out, DHALF, 0, nullptr, scale, DHALF,
            blockIdx.y * 128, blockIdx.x * 128);
}

// Grid (8, 32).
__global__ __launch_bounds__(256, 2) void outproj_kernel(
    const uint16_t* __restrict__ O, const uint16_t* __restrict__ Wob,
    const float* __restrict__ bo, float* __restrict__ Y)
{
    gemm128(O, DHALF, Wob, DHALF, Y, DMODEL, 1, bo, 1.0f, DHALF,
            blockIdx.y * 128, blockIdx.x * 128);
}

// ---------------------------------------------------------------------------
// Split-K flash attention (R20, ns=2). 512 threads / 8 waves; each wave owns
// 32 q-rows (q-block 256); KVBLK=128 as two 64-key halves. P in registers:
// swapped QK^T mfma(K,Q) gives lane (lo,quad) P[q=lo] at keys 16t+4quad+r;
// V staged key-permuted so PV's B-slot order matches P's register order.
// 2-buffer Ks/Vt, 1 barrier/tile. XCD panel swizzle: the 16 blocks sharing a
// (h,sp) K/V panel land in one dispatch residue class mod 8.
// ---------------------------------------------------------------------------
__global__ __launch_bounds__(512) void attn_kernel(
    const uint16_t* __restrict__ Q, const uint16_t* __restrict__ Kb,
    const uint16_t* __restrict__ Vb, uint16_t* __restrict__ Op,
    float* __restrict__ lbuf, int kspan)
{
    __shared__ __align__(16) uint16_t Ks[2][128 * 40];  // K tile [key][d]
    __shared__ __align__(16) uint16_t Vt[2][32 * 128];  // V^T [d][perm(key)], swizzled

    const int tid  = threadIdx.x;
    const int lane = tid & 63;
    const int wv   = tid >> 6;          // 0..7
    const int lo   = lane & 15;
    const int quad = lane >> 4;

    const int f  = blockIdx.x + 16 * blockIdx.y + 256 * blockIdx.z;
    const int pp = (f & 7) | ((f >> 7) << 3);
    const int h  = pp & 15;
    const int sp = pp >> 4;
    const int q0 = ((f >> 3) & 15) * 256;

    const int srow = tid >> 2;          // 0..127: staged K/V key row
    const int skq  = (tid & 3) * 8;

    const facc4 ZACC = {0.f, 0.f, 0.f, 0.f};

    bfrag8 qf[2];
    qf[0] = *(const bfrag8*)&Q[(size_t)(q0 + wv * 32 + lo) * DHALF + h * DH + quad * 8];
    qf[1] = *(const bfrag8*)&Q[(size_t)(q0 + wv * 32 + 16 + lo) * DHALF + h * DH + quad * 8];

    bfrag8 ones;
#pragma unroll
    for (int j = 0; j < 8; ++j) ones[j] = (short)0x3F80;  // bf16 1.0

    int vt_w[8];
    {
        int pb = ((srow >> 5) << 2) | ((srow >> 2) & 3);   // p >> 3, 0..15
        int pw = (((srow >> 4) & 1) << 2) | (srow & 3);    // p & 7
#pragma unroll
        for (int j = 0; j < 8; ++j) {
            int d  = skq + j;
            int Rd = ((d & 7) + 2 * (d >> 3)) & 7;
            vt_w[j] = d * 128 + (((pb + Rd) & 15) << 3) + pw;
        }
    }
    int vt_r[4][2];
#pragma unroll
    for (int dt = 0; dt < 2; ++dt) {
        int d  = dt * 16 + lo;
        int Rd = ((d & 7) + 2 * (d >> 3)) & 7;
#pragma unroll
        for (int c = 0; c < 4; ++c)
            vt_r[c][dt] = d * 128 + ((((c * 4 + quad) + Rd) & 15) << 3);
    }
    const int ks_r = lo * 40 + quad * 8;

    const uint16_t* kp = &Kb[(size_t)(sp * kspan + srow) * DHALF + h * DH + skq];
    const uint16_t* vp = &Vb[(size_t)(sp * kspan + srow) * DHALF + h * DH + skq];

    facc4 oacc[2][2], oaccL[2];
    oacc[0][0] = ZACC; oacc[0][1] = ZACC;
    oacc[1][0] = ZACC; oacc[1][1] = ZACC;
    oaccL[0] = ZACC; oaccL[1] = ZACC;

    float4 kreg = *(const float4*)kp;
    float4 vreg = *(const float4*)vp;
    kp += 128 * DHALF;
    vp += 128 * DHALF;

#define STAGE(BUF) do {                                                       \
        *(float4*)&Ks[BUF][srow * 40 + skq] = kreg;                           \
        const uint16_t* vsp = (const uint16_t*)&vreg;                         \
        _Pragma("unroll")                                                     \
        for (int j = 0; j < 8; ++j) Vt[BUF][vt_w[j]] = vsp[j];                \
    } while (0)

#define HALF(BUF, HH) do {                                                    \
        uint2 w0[4], w1[4];                                                   \
        _Pragma("unroll")                                                     \
        for (int t4 = 0; t4 < 4; ++t4) {                                      \
            bfrag8 kf = *(const bfrag8*)&Ks[BUF][(4 * HH + t4) * 640 + ks_r]; \
            facc4 s0 = MFMA_BF16(kf, qf[0], ZACC);                            \
            facc4 s1 = MFMA_BF16(kf, qf[1], ZACC);                            \
            uint32_t a0 = __float_as_uint(__builtin_amdgcn_exp2f(s0[0])) + 0x8000u; \
            uint32_t a1 = __float_as_uint(__builtin_amdgcn_exp2f(s0[1])) + 0x8000u; \
            uint32_t a2 = __float_as_uint(__builtin_amdgcn_exp2f(s0[2])) + 0x8000u; \
            uint32_t a3 = __float_as_uint(__builtin_amdgcn_exp2f(s0[3])) + 0x8000u; \
            w0[t4].x = __builtin_amdgcn_perm(a1, a0, 0x07060302u);            \
            w0[t4].y = __builtin_amdgcn_perm(a3, a2, 0x07060302u);            \
            uint32_t b0 = __float_as_uint(__builtin_amdgcn_exp2f(s1[0])) + 0x8000u; \
            uint32_t b1 = __float_as_uint(__builtin_amdgcn_exp2f(s1[1])) + 0x8000u; \
            uint32_t b2 = __float_as_uint(__builtin_amdgcn_exp2f(s1[2])) + 0x8000u; \
            uint32_t b3 = __float_as_uint(__builtin_amdgcn_exp2f(s1[3])) + 0x8000u; \
            w1[t4].x = __builtin_amdgcn_perm(b1, b0, 0x07060302u);            \
            w1[t4].y = __builtin_amdgcn_perm(b3, b2, 0x07060302u);            \
        }                                                                     \
        union PU { uint2 u2[2]; bfrag8 f; } pu;                               \
        bfrag8 pf0[2], pf1[2];                                                \
        pu.u2[0] = w0[0]; pu.u2[1] = w0[1]; pf0[0] = pu.f;                    \
        pu.u2[0] = w0[2]; pu.u2[1] = w0[3]; pf0[1] = pu.f;                    \
        pu.u2[0] = w1[0]; pu.u2[1] = w1[1]; pf1[0] = pu.f;                    \
        pu.u2[0] = w1[2]; pu.u2[1] = w1[3]; pf1[1] = pu.f;                    \
        _Pragma("unroll")                                                     \
        for (int cc = 0; cc < 2; ++cc) {                                      \
            _Pragma("unroll")                                                 \
            for (int dt = 0; dt < 2; ++dt) {                                  \
                bfrag8 vf = *(const bfrag8*)&Vt[BUF][vt_r[2 * HH + cc][dt]];  \
                oacc[0][dt] = MFMA_BF16(pf0[cc], vf, oacc[0][dt]);            \
                oacc[1][dt] = MFMA_BF16(pf1[cc], vf, oacc[1][dt]);            \
            }                                                                 \
            oaccL[0] = MFMA_BF16(pf0[cc], ones, oaccL[0]);                    \
            oaccL[1] = MFMA_BF16(pf1[cc], ones, oaccL[1]);                    \
        }                                                                     \
    } while (0)

#define TILE(BUF) do { HALF(BUF, 0); HALF(BUF, 1); } while (0)

    STAGE(0);
    __syncthreads();

    const int nt = kspan >> 7;  // 16 at ns=2; always even
    for (int t = 0; t < nt; t += 2) {
        kreg = *(const float4*)kp;
        vreg = *(const float4*)vp;
        kp += 128 * DHALF; vp += 128 * DHALF;
        TILE(0);
        STAGE(1);
        __syncthreads();

        const bool more = (t + 2 < nt);
        if (more) {
            kreg = *(const float4*)kp;
            vreg = *(const float4*)vp;
            kp += 128 * DHALF; vp += 128 * DHALF;
        }
        TILE(1);
        if (more) {
            STAGE(0);
            __syncthreads();
        }
    }
#undef STAGE
#undef HALF
#undef TILE

    if (lo == 0) {
#pragma unroll
        for (int g = 0; g < 2; ++g)
#pragma unroll
            for (int r = 0; r < 4; ++r)
                lbuf[((size_t)sp * NH + h) * SEQ + q0 + wv * 32 + g * 16 + quad * 4 + r] =
                    oaccL[g][r];
    }

    uint16_t* Od = Op + (size_t)sp * SEQ * DHALF;
#pragma unroll
    for (int g = 0; g < 2; ++g) {
#pragma unroll
        for (int r = 0; r < 4; ++r) {
            int row = q0 + wv * 32 + g * 16 + quad * 4 + r;
            Od[(size_t)row * DHALF + h * DH + lo]      = f2b(oacc[g][0][r]);  // unnormalized
            Od[(size_t)row * DHALF + h * DH + 16 + lo] = f2b(oacc[g][1][r]);
        }
    }
}

// O = sum_sp(Op_sp) / sum_sp(l_sp); 1 thread = 8 cols (within one head).
__global__ __launch_bounds__(256) void combine_kernel(
    const uint16_t* __restrict__ Op, const float* __restrict__ lbuf,
    uint16_t* __restrict__ O, int ns)
{
    int t   = blockIdx.x * 256 + threadIdx.x;
    int row = t >> 6;
    int cb  = (t & 63) << 3;
    int h   = cb >> 5;
    float l = 0.f;
    float acc[8] = {0.f, 0.f, 0.f, 0.f, 0.f, 0.f, 0.f, 0.f};
    for (int sp = 0; sp < ns; ++sp) {
        l += lbuf[((size_t)sp * NH + h) * SEQ + row];
        bfrag8 a = *(const bfrag8*)&Op[(size_t)sp * SEQ * DHALF + (size_t)row * DHALF + cb];
#pragma unroll
        for (int j = 0; j < 8; ++j) acc[j] += b2f((uint16_t)a[j]);
    }
    float inv = 1.0f / l;
    bfrag8 o;
#pragma unroll
    for (int j = 0; j < 8; ++j) o[j] = (short)f2b(acc[j] * inv);
    *(bfrag8*)&O[(size_t)row * DHALF + cb] = o;
}

extern "C" void kernel_launch(void* const* d_in, const int* in_sizes, int n_in,
                              void* d_out, int out_size, void* d_ws, size_t ws_size,
                              hipStream_t stream)
{
    const float* x  = (const float*)d_in[0];
    const float* Wq = (const float*)d_in[1];
    const float* Wk = (const float*)d_in[2];
    const float* Wv = (const float*)d_in[3];
    const float* Wo = (const float*)d_in[4];
    const float* bo = (const float*)d_in[5];

    // ws (u16 elems): Wqb/Wkb/Wvb 256K ea | Wob 512K | Q,K,V,O 2M ea | Op 2x2M
    // then lbuf (2*NH*SEQ fp32). xb (bf16 x left half) aliases the O slot:
    // written by convert_w, read by qkv, dead before combine writes O.
    const int ns = 2;

    uint16_t* Wqb = (uint16_t*)d_ws;
    uint16_t* Wkb = Wqb + (size_t)DHALF * DHALF;
    uint16_t* Wvb = Wkb + (size_t)DHALF * DHALF;
    uint16_t* Wob = Wvb + (size_t)DHALF * DHALF;
    uint16_t* Q   = Wob + (size_t)DMODEL * DHALF;
    uint16_t* K   = Q + (size_t)SEQ * DHALF;
    uint16_t* V   = K + (size_t)SEQ * DHALF;
    uint16_t* O   = V + (size_t)SEQ * DHALF;
    uint16_t* Op  = O + (size_t)SEQ * DHALF;
    float*  lbuf  = (float*)(Op + (size_t)ns * SEQ * DHALF);
    uint16_t* xb  = O;  // alias: live only convert_w -> qkv

    convert_w<<<1664, 256, 0, stream>>>(Wq, Wk, Wv, Wo, x, Wqb, Wkb, Wvb, Wob, xb);
    qkv_kernel<<<dim3(DHALF / 128, SEQ / 128, 3), 256, 0, stream>>>(
        xb, Wqb, Wkb, Wvb, Q, K, V);
    attn_kernel<<<dim3(SEQ / 256, NH, ns), 512, 0, stream>>>(Q, K, V, Op, lbuf, SEQ / ns);
    combine_kernel<<<1024, 256, 0, stream>>>(Op, lbuf, O, ns);
    outproj_kernel<<<dim3(DMODEL / 128, SEQ / 128), 256, 0, stream>>>(
        O, Wob, bo, (float*)d_out);
}

// Round 18
// 158.452 us; speedup vs baseline: 1.0599x; 1.0112x over previous
//
#include <hip/hip_runtime.h>
#include <stdint.h>

// MultiHeadSelfAttention: E=1024, H=16, S=4096, half=512, Dh=32, scale=sqrt(64)=8
// R25 = R24/R20 (best measured, 159.8-160.2us) + ONE change: XCD-aware block
// swizzle on the qkv and outproj grids (1D launch + bijective decode) so all
// blocks sharing an A row-panel land in one dispatch-residue class mod 8
// (= one XCD's L2 fetches each panel once). attn/convert/combine untouched.
// Structure: weights+x -> bf16 once; 128x128 BK=64 GEMMs with global_load_lds
// DMA staging and both-sides XOR chunk swizzle; split-K (ns=2) flash attention
// with 8 waves x 32 q-rows, KVBLK=128, P entirely in registers via swapped
// QK^T + key-permuted V staging, ones-column l-accumulation; XCD panel swizzle.

#define SEQ    4096
#define DMODEL 1024
#define DHALF  512
#define NH     16
#define DH     32

typedef __attribute__((ext_vector_type(4))) float facc4;
typedef __attribute__((ext_vector_type(8))) short bfrag8;

#define MFMA_BF16(a, b, c) __builtin_amdgcn_mfma_f32_16x16x32_bf16((a), (b), (c), 0, 0, 0)

// global -> LDS direct DMA, 16B per lane; LDS dest = base + lane*16 (HW).
static __device__ __forceinline__ void gll16(const void* g, void* l) {
    typedef const __attribute__((address_space(1))) void GV;
    typedef __attribute__((address_space(3))) void LV;
    __builtin_amdgcn_global_load_lds((GV*)g, (LV*)l, 16, 0, 0);
}

static __device__ __forceinline__ uint16_t f2b(float x) {
    uint32_t u = __float_as_uint(x);
    return (uint16_t)((u + 0x7FFFu + ((u >> 16) & 1u)) >> 16);  // RNE
}
static __device__ __forceinline__ float b2f(uint16_t b) {
    return __uint_as_float(((uint32_t)b) << 16);
}

// 8x fp32 -> 8x bf16 (round-half-away; ties measure-small) via 2add+1perm pairs
static __device__ __forceinline__ bfrag8 cvt8perm(float4 a, float4 b) {
    uint32_t u0 = __float_as_uint(a.x) + 0x8000u, u1 = __float_as_uint(a.y) + 0x8000u;
    uint32_t u2 = __float_as_uint(a.z) + 0x8000u, u3 = __float_as_uint(a.w) + 0x8000u;
    uint32_t u4 = __float_as_uint(b.x) + 0x8000u, u5 = __float_as_uint(b.y) + 0x8000u;
    uint32_t u6 = __float_as_uint(b.z) + 0x8000u, u7 = __float_as_uint(b.w) + 0x8000u;
    union { uint32_t w[4]; bfrag8 r; } u;
    u.w[0] = __builtin_amdgcn_perm(u1, u0, 0x07060302u);
    u.w[1] = __builtin_amdgcn_perm(u3, u2, 0x07060302u);
    u.w[2] = __builtin_amdgcn_perm(u5, u4, 0x07060302u);
    u.w[3] = __builtin_amdgcn_perm(u7, u6, 0x07060302u);
    return u.r;
}

// Weights fp32->bf16: blocks [0,128) Wq, [128,256) Wk, [256,384) Wv, [384,640) Wo.
// Blocks [640,1664): x left-half fp32 -> xb bf16 (4096x512, row-major).
__global__ __launch_bounds__(256) void convert_w(
    const float* __restrict__ Wq, const float* __restrict__ Wk,
    const float* __restrict__ Wv, const float* __restrict__ Wo,
    const float* __restrict__ x,
    uint16_t* __restrict__ q, uint16_t* __restrict__ k,
    uint16_t* __restrict__ v, uint16_t* __restrict__ o,
    uint16_t* __restrict__ xb)
{
    int zz = blockIdx.x;
    if (zz >= 640) {
        size_t g = (size_t)(zz - 640) * 2048 + (size_t)threadIdx.x * 8;
        int row = (int)(g >> 9);
        int col = (int)(g & 511);
        const float* src = &x[(size_t)row * DMODEL + col];
        float4 a = *(const float4*)src;
        float4 b = *(const float4*)(src + 4);
        *(bfrag8*)&xb[g] = cvt8perm(a, b);
        return;
    }
    const float* src; uint16_t* dst; size_t off;
    if      (zz < 128) { src = Wq; dst = q; off = (size_t)zz * 2048; }
    else if (zz < 256) { src = Wk; dst = k; off = (size_t)(zz - 128) * 2048; }
    else if (zz < 384) { src = Wv; dst = v; off = (size_t)(zz - 256) * 2048; }
    else               { src = Wo; dst = o; off = (size_t)(zz - 384) * 2048; }
    size_t i = off + (size_t)threadIdx.x * 8;
    float4 a = *(const float4*)&src[i];
    float4 b = *(const float4*)&src[i + 4];
    *(bfrag8*)&dst[i] = cvt8perm(a, b);
}

// ---------------------------------------------------------------------------
// 128x128-tile bf16 GEMM, BK=64, double-buffered, global_load_lds staging.
// LDS tile: lane-linear [128 rows][64 u16]. Chunk swizzle: phys 16B chunk c of
// row r holds logical k-chunk c^(r&7); DMA source applies the inverse per lane;
// ds_read applies it on the read side. ONE barrier per 64-K. Swapped-operand
// MFMA: lane (lo,quad) holds C[row=..+lo][col=..+quad*4+r]. (R20-proven)
// ---------------------------------------------------------------------------
__device__ __forceinline__ void gemm128(
    const uint16_t* __restrict__ A, int lda,
    const uint16_t* __restrict__ B, int ldb,
    void* __restrict__ C, int ldc, int cF32,
    const float* __restrict__ bias, float scale,
    int Kd, int m0, int n0)
{
    __shared__ __align__(16) uint16_t As[2][128 * 64];
    __shared__ __align__(16) uint16_t Bs[2][128 * 64];

    const int tid  = threadIdx.x;
    const int lane = tid & 63;
    const int wv   = tid >> 6;
    const int lo   = lane & 15;
    const int quad = lane >> 4;
    const int rb   = (wv >> 1) * 64;
    const int cb   = (wv & 1) * 64;

    const facc4 ZACC = {0.f, 0.f, 0.f, 0.f};
    facc4 acc[4][4];
#pragma unroll
    for (int i = 0; i < 4; ++i)
#pragma unroll
        for (int j = 0; j < 4; ++j) acc[i][j] = ZACC;

    const int lrow8 = lane >> 3;                      // 0..7
    const int scol  = (((lane & 7) ^ lrow8) << 3);    // swizzled source k-col (u16)
    const uint16_t* gA[4];
    const uint16_t* gB[4];
#pragma unroll
    for (int ii = 0; ii < 4; ++ii) {
        gA[ii] = &A[(size_t)(m0 + wv * 32 + ii * 8 + lrow8) * lda + scol];
        gB[ii] = &B[(size_t)(n0 + wv * 32 + ii * 8 + lrow8) * ldb + scol];
    }
    const int dd[4] = { wv * 2048, wv * 2048 + 512, wv * 2048 + 1024, wv * 2048 + 1536 };

    const int rdo0 = lo * 64 + (((quad) ^ (lo & 7)) << 3);
    const int rdo1 = lo * 64 + (((4 + quad) ^ (lo & 7)) << 3);

#pragma unroll
    for (int ii = 0; ii < 4; ++ii) {
        gll16(gA[ii], &As[0][dd[ii]]);
        gll16(gB[ii], &Bs[0][dd[ii]]);
    }
    __syncthreads();   // drains vmcnt -> tile 0 resident

    int p = 0;
    for (int kt = 0; kt < Kd; kt += 64) {
        const bool more = (kt + 64 < Kd);
        if (more) {
#pragma unroll
            for (int ii = 0; ii < 4; ++ii) {
                gll16(gA[ii] + kt + 64, &As[1 - p][dd[ii]]);
                gll16(gB[ii] + kt + 64, &Bs[1 - p][dd[ii]]);
            }
        }

        {   // k-half 0
            bfrag8 af[4], bf[4];
#pragma unroll
            for (int i = 0; i < 4; ++i) {
                af[i] = *(const bfrag8*)&As[p][rb * 64 + i * 1024 + rdo0];
                bf[i] = *(const bfrag8*)&Bs[p][cb * 64 + i * 1024 + rdo0];
            }
#pragma unroll
            for (int i = 0; i < 4; ++i)
#pragma unroll
                for (int j = 0; j < 4; ++j)
                    acc[i][j] = MFMA_BF16(bf[j], af[i], acc[i][j]);  // swapped
        }
        {   // k-half 1
            bfrag8 af[4], bf[4];
#pragma unroll
            for (int i = 0; i < 4; ++i) {
                af[i] = *(const bfrag8*)&As[p][rb * 64 + i * 1024 + rdo1];
                bf[i] = *(const bfrag8*)&Bs[p][cb * 64 + i * 1024 + rdo1];
            }
#pragma unroll
            for (int i = 0; i < 4; ++i)
#pragma unroll
                for (int j = 0; j < 4; ++j)
                    acc[i][j] = MFMA_BF16(bf[j], af[i], acc[i][j]);  // swapped
        }

        if (more) {
            __syncthreads();  // the only barrier per 64-K iter
            p ^= 1;
        }
    }

#pragma unroll
    for (int i = 0; i < 4; ++i) {
        const size_t row = (size_t)(m0 + rb + i * 16 + lo);
#pragma unroll
        for (int j = 0; j < 4; ++j) {
            const int colb = n0 + cb + j * 16 + quad * 4;
            float4 bv = {0.f, 0.f, 0.f, 0.f};
            if (bias) bv = *(const float4*)&bias[colb];
            float v0 = acc[i][j][0] * scale + bv.x;
            float v1 = acc[i][j][1] * scale + bv.y;
            float v2 = acc[i][j][2] * scale + bv.z;
            float v3 = acc[i][j][3] * scale + bv.w;
            if (cF32) {
                float4 o = {v0, v1, v2, v3};
                *(float4*)&((float*)C)[row * ldc + colb] = o;
            } else {
                uint2 o;
                o.x = (uint32_t)f2b(v0) | ((uint32_t)f2b(v1) << 16);
                o.y = (uint32_t)f2b(v2) | ((uint32_t)f2b(v3) << 16);
                *(uint2*)&((uint16_t*)C)[row * ldc + colb] = o;
            }
        }
    }
}

#define SC_Q (0.125f * 1.4426950408889634f)  // softmax scale * log2(e), folded into Q

// QKV from pre-converted bf16 xb. 1D grid(384) with XCD panel swizzle:
// c=F&7, s=F>>3; by=4c+(s&3), u=s>>2, bx=u&3, z=u>>2. Bijective; the 12
// blocks {bx,z} sharing A-panel `by` all land in residue class c (one XCD).
__global__ __launch_bounds__(256, 2) void qkv_kernel(
    const uint16_t* __restrict__ xb,
    const uint16_t* __restrict__ Wqb, const uint16_t* __restrict__ Wkb,
    const uint16_t* __restrict__ Wvb,
    uint16_t* __restrict__ Q, uint16_t* __restrict__ K, uint16_t* __restrict__ V)
{
    const int F  = blockIdx.x;
    const int c  = F & 7;
    const int s  = F >> 3;
    const int by = 4 * c + (s & 3);
    const int u  = s >> 2;
    const int bx = u & 3;
    const int z  = u >> 2;
    const uint16_t* W = (z == 0) ? Wqb : (z == 1) ? Wkb : Wvb;
    uint16_t* Out     = (z == 0) ? Q   : (z == 1) ? K   : V;
    float scale       = (z == 0) ? SC_Q : 1.0f;
    gemm128(xb, DHALF, W, DHALF, Out, DHALF, 0, nullptr, scale, DHALF,
            by * 128, bx * 128);
}

// 1D grid(256) with XCD panel swizzle: c=F&7, s=F>>3; by=4c+(s&3), bx=s>>2.
// The 8 bx-blocks sharing O-panel `by` all land in residue class c.
__global__ __launch_bounds__(256, 2) void outproj_kernel(
    const uint16_t* __restrict__ O, const uint16_t* __restrict__ Wob,
    const float* __restrict__ bo, float* __restrict__ Y)
{
    const int F  = blockIdx.x;
    const int c  = F & 7;
    const int s  = F >> 3;
    const int by = 4 * c + (s & 3);
    const int bx = s >> 2;
    gemm128(O, DHALF, Wob, DHALF, Y, DMODEL, 1, bo, 1.0f, DHALF,
            by * 128, bx * 128);
}

// ---------------------------------------------------------------------------
// Split-K flash attention (R20, ns=2). 512 threads / 8 waves; each wave owns
// 32 q-rows (q-block 256); KVBLK=128 as two 64-key halves. P in registers:
// swapped QK^T mfma(K,Q) gives lane (lo,quad) P[q=lo] at keys 16t+4quad+r;
// V staged key-permuted so PV's B-slot order matches P's register order.
// 2-buffer Ks/Vt, 1 barrier/tile. XCD panel swizzle: the 16 blocks sharing a
// (h,sp) K/V panel land in one dispatch residue class mod 8.
// ---------------------------------------------------------------------------
__global__ __launch_bounds__(512) void attn_kernel(
    const uint16_t* __restrict__ Q, const uint16_t* __restrict__ Kb,
    const uint16_t* __restrict__ Vb, uint16_t* __restrict__ Op,
    float* __restrict__ lbuf, int kspan)
{
    __shared__ __align__(16) uint16_t Ks[2][128 * 40];  // K tile [key][d]
    __shared__ __align__(16) uint16_t Vt[2][32 * 128];  // V^T [d][perm(key)], swizzled

    const int tid  = threadIdx.x;
    const int lane = tid & 63;
    const int wv   = tid >> 6;          // 0..7
    const int lo   = lane & 15;
    const int quad = lane >> 4;

    const int f  = blockIdx.x + 16 * blockIdx.y + 256 * blockIdx.z;
    const int pp = (f & 7) | ((f >> 7) << 3);
    const int h  = pp & 15;
    const int sp = pp >> 4;
    const int q0 = ((f >> 3) & 15) * 256;

    const int srow = tid >> 2;          // 0..127: staged K/V key row
    const int skq  = (tid & 3) * 8;

    const facc4 ZACC = {0.f, 0.f, 0.f, 0.f};

    bfrag8 qf[2];
    qf[0] = *(const bfrag8*)&Q[(size_t)(q0 + wv * 32 + lo) * DHALF + h * DH + quad * 8];
    qf[1] = *(const bfrag8*)&Q[(size_t)(q0 + wv * 32 + 16 + lo) * DHALF + h * DH + quad * 8];

    bfrag8 ones;
#pragma unroll
    for (int j = 0; j < 8; ++j) ones[j] = (short)0x3F80;  // bf16 1.0

    int vt_w[8];
    {
        int pb = ((srow >> 5) << 2) | ((srow >> 2) & 3);   // p >> 3, 0..15
        int pw = (((srow >> 4) & 1) << 2) | (srow & 3);    // p & 7
#pragma unroll
        for (int j = 0; j < 8; ++j) {
            int d  = skq + j;
            int Rd = ((d & 7) + 2 * (d >> 3)) & 7;
            vt_w[j] = d * 128 + (((pb + Rd) & 15) << 3) + pw;
        }
    }
    int vt_r[4][2];
#pragma unroll
    for (int dt = 0; dt < 2; ++dt) {
        int d  = dt * 16 + lo;
        int Rd = ((d & 7) + 2 * (d >> 3)) & 7;
#pragma unroll
        for (int c = 0; c < 4; ++c)
            vt_r[c][dt] = d * 128 + ((((c * 4 + quad) + Rd) & 15) << 3);
    }
    const int ks_r = lo * 40 + quad * 8;

    const uint16_t* kp = &Kb[(size_t)(sp * kspan + srow) * DHALF + h * DH + skq];
    const uint16_t* vp = &Vb[(size_t)(sp * kspan + srow) * DHALF + h * DH + skq];

    facc4 oacc[2][2], oaccL[2];
    oacc[0][0] = ZACC; oacc[0][1] = ZACC;
    oacc[1][0] = ZACC; oacc[1][1] = ZACC;
    oaccL[0] = ZACC; oaccL[1] = ZACC;

    float4 kreg = *(const float4*)kp;
    float4 vreg = *(const float4*)vp;
    kp += 128 * DHALF;
    vp += 128 * DHALF;

#define STAGE(BUF) do {                                                       \
        *(float4*)&Ks[BUF][srow * 40 + skq] = kreg;                           \
        const uint16_t* vsp = (const uint16_t*)&vreg;                         \
        _Pragma("unroll")                                                     \
        for (int j = 0; j < 8; ++j) Vt[BUF][vt_w[j]] = vsp[j];                \
    } while (0)

#define HALF(BUF, HH) do {                                                    \
        uint2 w0[4], w1[4];                                                   \
        _Pragma("unroll")                                                     \
        for (int t4 = 0; t4 < 4; ++t4) {                                      \
            bfrag8 kf = *(const bfrag8*)&Ks[BUF][(4 * HH + t4) * 640 + ks_r]; \
            facc4 s0 = MFMA_BF16(kf, qf[0], ZACC);                            \
            facc4 s1 = MFMA_BF16(kf, qf[1], ZACC);                            \
            uint32_t a0 = __float_as_uint(__builtin_amdgcn_exp2f(s0[0])) + 0x8000u; \
            uint32_t a1 = __float_as_uint(__builtin_amdgcn_exp2f(s0[1])) + 0x8000u; \
            uint32_t a2 = __float_as_uint(__builtin_amdgcn_exp2f(s0[2])) + 0x8000u; \
            uint32_t a3 = __float_as_uint(__builtin_amdgcn_exp2f(s0[3])) + 0x8000u; \
            w0[t4].x = __builtin_amdgcn_perm(a1, a0, 0x07060302u);            \
            w0[t4].y = __builtin_amdgcn_perm(a3, a2, 0x07060302u);            \
            uint32_t b0 = __float_as_uint(__builtin_amdgcn_exp2f(s1[0])) + 0x8000u; \
            uint32_t b1 = __float_as_uint(__builtin_amdgcn_exp2f(s1[1])) + 0x8000u; \
            uint32_t b2 = __float_as_uint(__builtin_amdgcn_exp2f(s1[2])) + 0x8000u; \
            uint32_t b3 = __float_as_uint(__builtin_amdgcn_exp2f(s1[3])) + 0x8000u; \
            w1[t4].x = __builtin_amdgcn_perm(b1, b0, 0x07060302u);            \
            w1[t4].y = __builtin_amdgcn_perm(b3, b2, 0x07060302u);            \
        }                                                                     \
        union PU { uint2 u2[2]; bfrag8 f; } pu;                               \
        bfrag8 pf0[2], pf1[2];                                                \
        pu.u2[0] = w0[0]; pu.u2[1] = w0[1]; pf0[0] = pu.f;                    \
        pu.u2[0] = w0[2]; pu.u2[1] = w0[3]; pf0[1] = pu.f;                    \
        pu.u2[0] = w1[0]; pu.u2[1] = w1[1]; pf1[0] = pu.f;                    \
        pu.u2[0] = w1[2]; pu.u2[1] = w1[3]; pf1[1] = pu.f;                    \
        _Pragma("unroll")                                                     \
        for (int cc = 0; cc < 2; ++cc) {                                      \
            _Pragma("unroll")                                                 \
            for (int dt = 0; dt < 2; ++dt) {                                  \
                bfrag8 vf = *(const bfrag8*)&Vt[BUF][vt_r[2 * HH + cc][dt]];  \
                oacc[0][dt] = MFMA_BF16(pf0[cc], vf, oacc[0][dt]);            \
                oacc[1][dt] = MFMA_BF16(pf1[cc], vf, oacc[1][dt]);            \
            }                                                                 \
            oaccL[0] = MFMA_BF16(pf0[cc], ones, oaccL[0]);                    \
            oaccL[1] = MFMA_BF16(pf1[cc], ones, oaccL[1]);                    \
        }                                                                     \
    } while (0)

#define TILE(BUF) do { HALF(BUF, 0); HALF(BUF, 1); } while (0)

    STAGE(0);
    __syncthreads();

    const int nt = kspan >> 7;  // 16 at ns=2; always even
    for (int t = 0; t < nt; t += 2) {
        kreg = *(const float4*)kp;
        vreg = *(const float4*)vp;
        kp += 128 * DHALF; vp += 128 * DHALF;
        TILE(0);
        STAGE(1);
        __syncthreads();

        const bool more = (t + 2 < nt);
        if (more) {
            kreg = *(const float4*)kp;
            vreg = *(const float4*)vp;
            kp += 128 * DHALF; vp += 128 * DHALF;
        }
        TILE(1);
        if (more) {
            STAGE(0);
            __syncthreads();
        }
    }
#undef STAGE
#undef HALF
#undef TILE

    if (lo == 0) {
#pragma unroll
        for (int g = 0; g < 2; ++g)
#pragma unroll
            for (int r = 0; r < 4; ++r)
                lbuf[((size_t)sp * NH + h) * SEQ + q0 + wv * 32 + g * 16 + quad * 4 + r] =
                    oaccL[g][r];
    }

    uint16_t* Od = Op + (size_t)sp * SEQ * DHALF;
#pragma unroll
    for (int g = 0; g < 2; ++g) {
#pragma unroll
        for (int r = 0; r < 4; ++r) {
            int row = q0 + wv * 32 + g * 16 + quad * 4 + r;
            Od[(size_t)row * DHALF + h * DH + lo]      = f2b(oacc[g][0][r]);  // unnormalized
            Od[(size_t)row * DHALF + h * DH + 16 + lo] = f2b(oacc[g][1][r]);
        }
    }
}

// O = sum_sp(Op_sp) / sum_sp(l_sp); 1 thread = 8 cols (within one head).
__global__ __launch_bounds__(256) void combine_kernel(
    const uint16_t* __restrict__ Op, const float* __restrict__ lbuf,
    uint16_t* __restrict__ O, int ns)
{
    int t   = blockIdx.x * 256 + threadIdx.x;
    int row = t >> 6;
    int cb  = (t & 63) << 3;
    int h   = cb >> 5;
    float l = 0.f;
    float acc[8] = {0.f, 0.f, 0.f, 0.f, 0.f, 0.f, 0.f, 0.f};
    for (int sp = 0; sp < ns; ++sp) {
        l += lbuf[((size_t)sp * NH + h) * SEQ + row];
        bfrag8 a = *(const bfrag8*)&Op[(size_t)sp * SEQ * DHALF + (size_t)row * DHALF + cb];
#pragma unroll
        for (int j = 0; j < 8; ++j) acc[j] += b2f((uint16_t)a[j]);
    }
    float inv = 1.0f / l;
    bfrag8 o;
#pragma unroll
    for (int j = 0; j < 8; ++j) o[j] = (short)f2b(acc[j] * inv);
    *(bfrag8*)&O[(size_t)row * DHALF + cb] = o;
}

extern "C" void kernel_launch(void* const* d_in, const int* in_sizes, int n_in,
                              void* d_out, int out_size, void* d_ws, size_t ws_size,
                              hipStream_t stream)
{
    const float* x  = (const float*)d_in[0];
    const float* Wq = (const float*)d_in[1];
    const float* Wk = (const float*)d_in[2];
    const float* Wv = (const float*)d_in[3];
    const float* Wo = (const float*)d_in[4];
    const float* bo = (const float*)d_in[5];

    // ws (u16 elems): Wqb/Wkb/Wvb 256K ea | Wob 512K | Q,K,V,O 2M ea | Op 2x2M
    // then lbuf (2*NH*SEQ fp32). xb (bf16 x left half) aliases the O slot:
    // written by convert_w, read by qkv, dead before combine writes O.
    const int ns = 2;

    uint16_t* Wqb = (uint16_t*)d_ws;
    uint16_t* Wkb = Wqb + (size_t)DHALF * DHALF;
    uint16_t* Wvb = Wkb + (size_t)DHALF * DHALF;
    uint16_t* Wob = Wvb + (size_t)DHALF * DHALF;
    uint16_t* Q   = Wob + (size_t)DMODEL * DHALF;
    uint16_t* K   = Q + (size_t)SEQ * DHALF;
    uint16_t* V   = K + (size_t)SEQ * DHALF;
    uint16_t* O   = V + (size_t)SEQ * DHALF;
    uint16_t* Op  = O + (size_t)SEQ * DHALF;
    float*  lbuf  = (float*)(Op + (size_t)ns * SEQ * DHALF);
    uint16_t* xb  = O;  // alias: live only convert_w -> qkv

    convert_w<<<1664, 256, 0, stream>>>(Wq, Wk, Wv, Wo, x, Wqb, Wkb, Wvb, Wob, xb);
    qkv_kernel<<<384, 256, 0, stream>>>(xb, Wqb, Wkb, Wvb, Q, K, V);
    attn_kernel<<<dim3(SEQ / 256, NH, ns), 512, 0, stream>>>(Q, K, V, Op, lbuf, SEQ / ns);
    combine_kernel<<<1024, 256, 0, stream>>>(Op, lbuf, O, ns);
    outproj_kernel<<<256, 256, 0, stream>>>(O, Wob, bo, (float*)d_out);
}